// Round 3
// baseline (739.589 us; speedup 1.0000x reference)
//
#include <hip/hip_runtime.h>

typedef unsigned short u16;
typedef unsigned int   u32;

#define NB   16      // batch
#define NC   128     // channels
#define NPIX 1024    // 32*32
#define NH   4       // heads
#define DH   32      // dim head

__device__ __forceinline__ float bf2f(u16 u) {
    return __uint_as_float(((u32)u) << 16);
}
__device__ __forceinline__ u16 f2bf(float f) {
    u32 u = __float_as_uint(f);
    u32 r = (u + 0x7fffu + ((u >> 16) & 1u)) >> 16;
    return (u16)r;
}
// dtype-agnostic loads: isf=1 -> fp32 data, isf=0 -> bf16 data
__device__ __forceinline__ float loadf(const void* p, int i, int isf) {
    return isf ? ((const float*)p)[i] : bf2f(((const u16*)p)[i]);
}
__device__ __forceinline__ float4 load4(const void* p, int i4, int isf) {
    if (isf) return ((const float4*)p)[i4];
    ushort4 u = ((const ushort4*)p)[i4];
    return make_float4(bf2f(u.x), bf2f(u.y), bf2f(u.z), bf2f(u.w));
}

// ---------------------------------------------------------------------------
// Kernel D: dtype detector. True-bf16 N(0,1) half-words never have bf16
// exponent >= 134 (|x|>=128); fp32 N(0,1) data read as u16 halfwords has
// ~25% such (uniform low-mantissa halves). One block.
// ---------------------------------------------------------------------------
__global__ __launch_bounds__(256) void detect_kernel(
        const void* __restrict__ x, int* __restrict__ flag) {
    __shared__ int cnt;
    if (threadIdx.x == 0) cnt = 0;
    __syncthreads();
    const u16* p = (const u16*)x;
    int c = 0;
    for (int i = threadIdx.x; i < 4096; i += 256) {
        int e = (p[i] >> 7) & 0xFF;
        if (e >= 134) ++c;
    }
    atomicAdd(&cnt, c);
    __syncthreads();
    if (threadIdx.x == 0) flag[0] = (cnt > 100) ? 1 : 0;
}

// ---------------------------------------------------------------------------
// Kernel 0: bias[h][n][m] = table[rel_index[n*N+m]][h]  (fp32 out)
// ---------------------------------------------------------------------------
__global__ __launch_bounds__(256) void bias_kernel(
        const int* __restrict__ rel, const void* __restrict__ table,
        float* __restrict__ biasb, const int* __restrict__ flag) {
    int isf = flag[0];
    int i = blockIdx.x * 256 + threadIdx.x;       // 4 * 1024 * 1024 total
    if (i >= 4 * 1024 * 1024) return;
    int h  = i >> 20;
    int nm = i & 0xFFFFF;
    int ri = rel[nm];
    biasb[i] = loadf(table, ri * NH + h, isf);
}

// ---------------------------------------------------------------------------
// Kernel 1: 3x3 conv (pad 1) for q/k/v, fp32 out + per-(proj,b) sum/sumsq
// grid (32 co-groups, 16 b, 3 proj), block 256
// ---------------------------------------------------------------------------
__global__ __launch_bounds__(256) void conv_kernel(
        const void* __restrict__ x,
        const void* __restrict__ w0, const void* __restrict__ w1,
        const void* __restrict__ w2,
        float* __restrict__ conv_out, float* __restrict__ stats,
        const int* __restrict__ flag) {
    __shared__ float xs[34 * 34];        // zero-haloed channel image
    __shared__ float wsh[4 * 128 * 9];   // 4 co x 128 ci x 9, fp32
    __shared__ float rs[8];

    int isf = flag[0];
    int t = threadIdx.x;
    int cog = blockIdx.x, b = blockIdx.y, j = blockIdx.z;
    const void* w = (j == 0) ? w0 : ((j == 1) ? w1 : w2);

    for (int i = t; i < 34 * 34; i += 256) xs[i] = 0.f;
    int wbase = cog * 4 * 1152;
    for (int i = t; i < 4608; i += 256) wsh[i] = loadf(w, wbase + i, isf);

    int col = t >> 6, l = t & 63;
    int ty = (l >> 3) << 2, tx = (l & 7) << 2;   // 4x4 pixel tile origin
    int srow = t >> 3, sxq = (t & 7) * 4;        // staging assignment

    float acc[16];
#pragma unroll
    for (int i = 0; i < 16; ++i) acc[i] = 0.f;

    int xbase4 = (b * (NC * NPIX) + srow * 32 + sxq) >> 2;

    for (int ci = 0; ci < 128; ++ci) {
        float4 u = load4(x, xbase4 + ci * (NPIX >> 2), isf);
        __syncthreads();                          // prev compute done
        xs[(srow + 1) * 34 + sxq + 1] = u.x;
        xs[(srow + 1) * 34 + sxq + 2] = u.y;
        xs[(srow + 1) * 34 + sxq + 3] = u.z;
        xs[(srow + 1) * 34 + sxq + 4] = u.w;
        __syncthreads();

        float wv[9];
#pragma unroll
        for (int k = 0; k < 9; ++k) wv[k] = wsh[col * 1152 + ci * 9 + k];

        float p[6][6];
#pragma unroll
        for (int rr = 0; rr < 6; ++rr)
#pragma unroll
            for (int cc = 0; cc < 6; ++cc)
                p[rr][cc] = xs[(ty + rr) * 34 + tx + cc];

#pragma unroll
        for (int iy = 0; iy < 4; ++iy)
#pragma unroll
            for (int ix = 0; ix < 4; ++ix) {
                float a = acc[iy * 4 + ix];
#pragma unroll
                for (int dy = 0; dy < 3; ++dy)
#pragma unroll
                    for (int dx = 0; dx < 3; ++dx)
                        a = fmaf(p[iy + dy][ix + dx], wv[dy * 3 + dx], a);
                acc[iy * 4 + ix] = a;
            }
    }

    int co = cog * 4 + col;
    float* outp = conv_out + (((size_t)j * NB + b) * NC + co) * NPIX;
    float s = 0.f, s2 = 0.f;
#pragma unroll
    for (int iy = 0; iy < 4; ++iy) {
        float4 v = make_float4(acc[iy * 4 + 0], acc[iy * 4 + 1],
                               acc[iy * 4 + 2], acc[iy * 4 + 3]);
        *(float4*)&outp[(ty + iy) * 32 + tx] = v;
        s += v.x + v.y + v.z + v.w;
        s2 = fmaf(v.x, v.x, fmaf(v.y, v.y, fmaf(v.z, v.z, fmaf(v.w, v.w, s2))));
    }
#pragma unroll
    for (int off = 32; off; off >>= 1) {
        s  += __shfl_down(s,  (unsigned)off, 64);
        s2 += __shfl_down(s2, (unsigned)off, 64);
    }
    int wid = t >> 6;
    if ((t & 63) == 0) { rs[wid] = s; rs[4 + wid] = s2; }
    __syncthreads();
    if (t == 0) {
        atomicAdd(&stats[(j * NB + b) * 2 + 0], rs[0] + rs[1] + rs[2] + rs[3]);
        atomicAdd(&stats[(j * NB + b) * 2 + 1], rs[4] + rs[5] + rs[6] + rs[7]);
    }
}

// ---------------------------------------------------------------------------
// Kernel 2: GroupNorm(1) + exact GELU + transpose (c,n)->(n,d heads layout)
// grid (4 ntiles, 4 h, 48 z=j*16+b), block 256
// ---------------------------------------------------------------------------
__global__ __launch_bounds__(256) void norm_kernel(
        const float* __restrict__ conv_out, const float* __restrict__ stats,
        const void* __restrict__ g0, const void* __restrict__ b0,
        const void* __restrict__ g1, const void* __restrict__ b1,
        const void* __restrict__ g2, const void* __restrict__ b2,
        float* __restrict__ qkv, const int* __restrict__ flag) {
    __shared__ float tile[32 * 257];
    int isf = flag[0];
    int t = threadIdx.x;
    int n0 = blockIdx.x * 256;
    int h = blockIdx.y;
    int z = blockIdx.z;
    int j = z >> 4;
    const void* gam = (j == 0) ? g0 : ((j == 1) ? g1 : g2);
    const void* bet = (j == 0) ? b0 : ((j == 1) ? b1 : b2);

    float sum = stats[z * 2], ss = stats[z * 2 + 1];
    const float inv = 1.0f / 131072.0f;
    float mean = sum * inv;
    float var  = fmaxf(ss * inv - mean * mean, 0.f);
    float rstd = rsqrtf(var + 1e-6f);

    const float* src = conv_out + ((size_t)z * NC + h * DH) * NPIX + n0;
#pragma unroll
    for (int cl = 0; cl < 32; ++cl) tile[cl * 257 + t] = src[cl * NPIX + t];
    __syncthreads();

    float* dst = qkv + (size_t)z * (NC * NPIX) + h * (NPIX * DH) + n0 * DH;
#pragma unroll
    for (int k = 0; k < 32; ++k) {
        int o = t + k * 256;
        int d = o & 31, nl = o >> 5;
        float v = tile[d * 257 + nl];
        v = (v - mean) * rstd * loadf(gam, h * DH + d, isf)
          + loadf(bet, h * DH + d, isf);
        v = 0.5f * v * (1.0f + erff(v * 0.70710678118654752f));   // exact GELU
        dst[o] = v;
    }
}

// ---------------------------------------------------------------------------
// Kernel 3: flash attention per (b,h,64-row q tile). grid (16,4,16), block 256
// qkv layout: [j][b][h][n][d] fp32; biasb fp32 [h][n][m]
// ---------------------------------------------------------------------------
__global__ __launch_bounds__(256) void attn_kernel(
        const float* __restrict__ qkv, const float* __restrict__ biasb,
        float* __restrict__ attf) {
    __shared__ float Qs[64 * 33];      // padded
    __shared__ float KT[32 * 64];      // K transposed: [d][m]
    __shared__ float Vs[64 * 32];
    __shared__ float Sb[64 * 65];      // padded scores
    __shared__ float red[4 * 64];
    __shared__ float mrow[64], lrow[64], arow[64];

    int t = threadIdx.x;
    int n0 = blockIdx.x * 64, h = blockIdx.y, b = blockIdx.z;

    size_t qoff = (size_t)b * (NC * NPIX) + h * (NPIX * DH) + n0 * DH;
    {
        const float4* qp = (const float4*)(qkv + qoff);
        float4 a = qp[t * 2], c = qp[t * 2 + 1];
        int f = t * 8, r = f >> 5, d = f & 31;
        float* dst = &Qs[r * 33 + d];
        dst[0] = a.x; dst[1] = a.y; dst[2] = a.z; dst[3] = a.w;
        dst[4] = c.x; dst[5] = c.y; dst[6] = c.z; dst[7] = c.w;
    }
    if (t < 64) { mrow[t] = -1e30f; lrow[t] = 0.f; }

    float o_[8] = {0, 0, 0, 0, 0, 0, 0, 0};
    int r_s = t & 63, mb = t >> 6, m16 = mb * 16;
    int r_o = t >> 2, d0 = (t & 3) * 8;
    __syncthreads();

    for (int kc = 0; kc < 16; ++kc) {
        size_t koff = (size_t)(NB * NC * NPIX) + (size_t)b * (NC * NPIX)
                    + h * (NPIX * DH) + (size_t)(kc * 64) * DH;
        size_t voff = koff + (size_t)(NB * NC * NPIX);
        {
            const float4* kp = (const float4*)(qkv + koff);
            float4 a = kp[t * 2], c = kp[t * 2 + 1];
            int f = t * 8, rr = f >> 5, dd = f & 31;
            KT[(dd + 0) * 64 + rr] = a.x; KT[(dd + 1) * 64 + rr] = a.y;
            KT[(dd + 2) * 64 + rr] = a.z; KT[(dd + 3) * 64 + rr] = a.w;
            KT[(dd + 4) * 64 + rr] = c.x; KT[(dd + 5) * 64 + rr] = c.y;
            KT[(dd + 6) * 64 + rr] = c.z; KT[(dd + 7) * 64 + rr] = c.w;
            const float4* vp = (const float4*)(qkv + voff);
            float4 va = vp[t * 2], vb = vp[t * 2 + 1];
            *(float4*)&Vs[rr * 32 + dd]     = va;
            *(float4*)&Vs[rr * 32 + dd + 4] = vb;
        }
        __syncthreads();

        // ---- scores: thread computes S[r_s][m16..m16+16) ----
        float sc[16];
        const float* bp = biasb + ((size_t)h << 20) + (size_t)(n0 + r_s) * NPIX
                        + kc * 64 + m16;
#pragma unroll
        for (int i = 0; i < 16; ++i) sc[i] = bp[i];
#pragma unroll 4
        for (int d = 0; d < 32; ++d) {
            float qv = Qs[r_s * 33 + d];
            const float4* kp = (const float4*)&KT[d * 64 + m16];
            float4 k0 = kp[0], k1 = kp[1], k2 = kp[2], k3 = kp[3];
            sc[0]  = fmaf(qv, k0.x, sc[0]);  sc[1]  = fmaf(qv, k0.y, sc[1]);
            sc[2]  = fmaf(qv, k0.z, sc[2]);  sc[3]  = fmaf(qv, k0.w, sc[3]);
            sc[4]  = fmaf(qv, k1.x, sc[4]);  sc[5]  = fmaf(qv, k1.y, sc[5]);
            sc[6]  = fmaf(qv, k1.z, sc[6]);  sc[7]  = fmaf(qv, k1.w, sc[7]);
            sc[8]  = fmaf(qv, k2.x, sc[8]);  sc[9]  = fmaf(qv, k2.y, sc[9]);
            sc[10] = fmaf(qv, k2.z, sc[10]); sc[11] = fmaf(qv, k2.w, sc[11]);
            sc[12] = fmaf(qv, k3.x, sc[12]); sc[13] = fmaf(qv, k3.y, sc[13]);
            sc[14] = fmaf(qv, k3.z, sc[14]); sc[15] = fmaf(qv, k3.w, sc[15]);
        }
        float lm = sc[0];
#pragma unroll
        for (int i = 1; i < 16; ++i) lm = fmaxf(lm, sc[i]);
        red[mb * 64 + r_s] = lm;
        __syncthreads();

        if (t < 64) {
            float mo = mrow[t];
            float mn = fmaxf(mo, fmaxf(fmaxf(red[t], red[64 + t]),
                                       fmaxf(red[128 + t], red[192 + t])));
            mrow[t] = mn;
            arow[t] = __expf(mo - mn);
        }
        __syncthreads();

        float mn = mrow[r_s];
        float ps = 0.f;
#pragma unroll
        for (int i = 0; i < 16; ++i) {
            float p = __expf(sc[i] - mn);
            Sb[r_s * 65 + m16 + i] = p;
            ps += p;
        }
        red[mb * 64 + r_s] = ps;
        __syncthreads();

        if (t < 64)
            lrow[t] = lrow[t] * arow[t] + red[t] + red[64 + t]
                    + red[128 + t] + red[192 + t];

        // ---- O update: thread owns (r_o, d0..d0+8) ----
        float al = arow[r_o];
#pragma unroll
        for (int i = 0; i < 8; ++i) o_[i] *= al;
#pragma unroll 4
        for (int m = 0; m < 64; ++m) {
            float p = Sb[r_o * 65 + m];
            const float4* vp = (const float4*)&Vs[m * 32 + d0];
            float4 va = vp[0], vb = vp[1];
            o_[0] = fmaf(p, va.x, o_[0]); o_[1] = fmaf(p, va.y, o_[1]);
            o_[2] = fmaf(p, va.z, o_[2]); o_[3] = fmaf(p, va.w, o_[3]);
            o_[4] = fmaf(p, vb.x, o_[4]); o_[5] = fmaf(p, vb.y, o_[5]);
            o_[6] = fmaf(p, vb.z, o_[6]); o_[7] = fmaf(p, vb.w, o_[7]);
        }
        __syncthreads();
    }

    float rl = 1.0f / lrow[r_o];
    size_t ooff = ((size_t)b * NPIX + n0 + r_o) * NC + h * DH + d0;
    *(float4*)(attf + ooff) =
        make_float4(o_[0] * rl, o_[1] * rl, o_[2] * rl, o_[3] * rl);
    *(float4*)(attf + ooff + 4) =
        make_float4(o_[4] * rl, o_[5] * rl, o_[6] * rl, o_[7] * rl);
}

// ---------------------------------------------------------------------------
// Kernel 4: 1x1 conv + bias. grid (32 ntiles, 16 b), block 256
// attf layout: [b][n][c] fp32; output dtype per flag
// ---------------------------------------------------------------------------
__global__ __launch_bounds__(256) void out_kernel(
        const float* __restrict__ attf, const void* __restrict__ ow,
        const void* __restrict__ ob, void* __restrict__ out,
        const int* __restrict__ flag) {
    __shared__ float aL[32 * 129];
    __shared__ float wL[128 * 128];
    int isf = flag[0];
    int t = threadIdx.x;
    int n0 = blockIdx.x * 32, b = blockIdx.y;

    const float4* ap = (const float4*)(attf + ((size_t)b * NPIX + n0) * NC);
#pragma unroll
    for (int k = 0; k < 4; ++k) {
        int fi = t + k * 256;                // 1024 float4 total
        float4 v = ap[fi];
        int fl = fi * 4, rw = fl >> 7, cl = fl & 127;
        float* dst = &aL[rw * 129 + cl];
        dst[0] = v.x; dst[1] = v.y; dst[2] = v.z; dst[3] = v.w;
    }
    for (int i = t; i < 128 * 128; i += 256) wL[i] = loadf(ow, i, isf);
    __syncthreads();

    int nl = t & 31, cg = t >> 5;            // 8 groups x 16 co
    const float* arow_ = &aL[nl * 129];
#pragma unroll
    for (int k = 0; k < 16; ++k) {
        int co = cg * 16 + k;
        const float* wr = &wL[co * 128];
        float acc = loadf(ob, co, isf);
#pragma unroll 16
        for (int ci = 0; ci < 128; ++ci)
            acc = fmaf(wr[ci], arow_[ci], acc);
        size_t oidx = ((size_t)b * NC + co) * NPIX + n0 + nl;
        if (isf) ((float*)out)[oidx] = acc;
        else     ((u16*)out)[oidx]   = f2bf(acc);
    }
}

// ---------------------------------------------------------------------------
// Workspace layout (peak ~48 MiB; buffer-lifetime aliasing):
//   [0,   448)                  stats (96 floats used)
//   [448, 452)                  dtype flag (int)
//   [512, 512+25165824)         qkv   fp32 [3][16][4][1024][32]
//   [A,   A+25165824)           conv  fp32  (A = 512+25165824)
//     after norm_kernel, conv region dead, reused:
//       biasb (fp32, 16777216 B) at A          (bias_kernel)
//       attf  (fp32,  8388608 B) at A+16777216 (attn_kernel)
// Order: memset stats -> detect -> conv -> norm -> bias -> attn -> out
// ---------------------------------------------------------------------------
extern "C" void kernel_launch(void* const* d_in, const int* in_sizes, int n_in,
                              void* d_out, int out_size, void* d_ws,
                              size_t ws_size, hipStream_t stream) {
    (void)in_sizes; (void)n_in; (void)out_size; (void)ws_size;
    const void* x     = d_in[0];
    const void* wq    = d_in[1];
    const void* gq    = d_in[2];
    const void* bq    = d_in[3];
    const void* wk    = d_in[4];
    const void* gk    = d_in[5];
    const void* bk    = d_in[6];
    const void* wv    = d_in[7];
    const void* gv    = d_in[8];
    const void* bv    = d_in[9];
    const void* table = d_in[10];
    const int*  rel   = (const int*)d_in[11];
    const void* ow    = d_in[12];
    const void* ob    = d_in[13];

    char* ws = (char*)d_ws;
    float* stats = (float*)(ws);                        // 448 B
    int*   flag  = (int*)(ws + 448);
    float* qkv   = (float*)(ws + 512);                  // 25,165,824 B
    char*  regA  = ws + 512 + 25165824;                 // 25,165,824 B region
    float* conv  = (float*)regA;                        // lifetime: conv->norm
    float* biasb = (float*)regA;                        // alias: bias->attn
    float* attf  = (float*)(regA + 16777216);           // alias: attn->out

    hipMemsetAsync(stats, 0, 96 * sizeof(float), stream);
    detect_kernel<<<1, 256, 0, stream>>>(x, flag);
    conv_kernel<<<dim3(32, 16, 3), 256, 0, stream>>>(x, wq, wk, wv, conv,
                                                     stats, flag);
    norm_kernel<<<dim3(4, 4, 48), 256, 0, stream>>>(conv, stats,
                                                    gq, bq, gk, bk, gv, bv,
                                                    qkv, flag);
    bias_kernel<<<16384, 256, 0, stream>>>(rel, table, biasb, flag);
    attn_kernel<<<dim3(16, 4, 16), 256, 0, stream>>>(qkv, biasb, attf);
    out_kernel<<<dim3(32, 16), 256, 0, stream>>>(attf, ow, ob, d_out, flag);
}

// Round 4
// 418.394 us; speedup vs baseline: 1.7677x; 1.7677x over previous
//
#include <hip/hip_runtime.h>

typedef unsigned short u16;
typedef unsigned int   u32;

#define NB   16      // batch
#define NC   128     // channels
#define NPIX 1024    // 32*32
#define NH   4       // heads
#define DH   32      // dim head

typedef __attribute__((ext_vector_type(8))) short short8;
typedef __attribute__((ext_vector_type(4))) float f32x4;

__device__ __forceinline__ float bf2f(u16 u) {
    return __uint_as_float(((u32)u) << 16);
}
__device__ __forceinline__ u16 f2bf(float f) {
    u32 u = __float_as_uint(f);
    u32 r = (u + 0x7fffu + ((u >> 16) & 1u)) >> 16;
    return (u16)r;
}
// dtype-agnostic loads: isf=1 -> fp32 data, isf=0 -> bf16 data
__device__ __forceinline__ float loadf(const void* p, int i, int isf) {
    return isf ? ((const float*)p)[i] : bf2f(((const u16*)p)[i]);
}
__device__ __forceinline__ float4 load4(const void* p, int i4, int isf) {
    if (isf) return ((const float4*)p)[i4];
    ushort4 u = ((const ushort4*)p)[i4];
    return make_float4(bf2f(u.x), bf2f(u.y), bf2f(u.z), bf2f(u.w));
}

// ---------------------------------------------------------------------------
// Kernel D: dtype detector (unchanged from round 3 — proven).
// ---------------------------------------------------------------------------
__global__ __launch_bounds__(256) void detect_kernel(
        const void* __restrict__ x, int* __restrict__ flag) {
    __shared__ int cnt;
    if (threadIdx.x == 0) cnt = 0;
    __syncthreads();
    const u16* p = (const u16*)x;
    int c = 0;
    for (int i = threadIdx.x; i < 4096; i += 256) {
        int e = (p[i] >> 7) & 0xFF;
        if (e >= 134) ++c;
    }
    atomicAdd(&cnt, c);
    __syncthreads();
    if (threadIdx.x == 0) flag[0] = (cnt > 100) ? 1 : 0;
}

// ---------------------------------------------------------------------------
// prep_w: Wt[j][tap][co][ci] bf16 from w_j OIHW [co][ci][ky][kx]
// total 3*9*128*128 = 442368 elements
// ---------------------------------------------------------------------------
__global__ __launch_bounds__(256) void prep_w(
        const void* __restrict__ w0, const void* __restrict__ w1,
        const void* __restrict__ w2, u16* __restrict__ Wt,
        const int* __restrict__ flag) {
    int isf = flag[0];
    int i = blockIdx.x * 256 + threadIdx.x;
    if (i >= 442368) return;
    int j   = i / 147456;
    int rr  = i % 147456;
    int tap = rr >> 14;          // /16384
    int co  = (rr >> 7) & 127;
    int ci  = rr & 127;
    const void* w = (j == 0) ? w0 : ((j == 1) ? w1 : w2);
    float v = loadf(w, (co * 128 + ci) * 9 + tap, isf);
    Wt[i] = f2bf(v);
}

// ---------------------------------------------------------------------------
// prep_x: xT[b][pix][ci] bf16 from x[b][ci][pix]. grid (8 pixg, 4 cig, 16 b)
// ---------------------------------------------------------------------------
__global__ __launch_bounds__(256) void prep_x(
        const void* __restrict__ x, u16* __restrict__ xT,
        const int* __restrict__ flag) {
    __shared__ float tile[32 * 129];
    int isf = flag[0];
    int t = threadIdx.x;
    int pixg = blockIdx.x, cig = blockIdx.y, b = blockIdx.z;

    int ci = t >> 3, px0 = (t & 7) * 16;
    int base = b * (NC * NPIX) + (cig * 32 + ci) * NPIX + pixg * 128 + px0;
#pragma unroll
    for (int u = 0; u < 4; ++u) {
        float4 v = load4(x, (base >> 2) + u, isf);
        float* d = &tile[ci * 129 + px0 + u * 4];
        d[0] = v.x; d[1] = v.y; d[2] = v.z; d[3] = v.w;
    }
    __syncthreads();
#pragma unroll
    for (int u = 0; u < 2; ++u) {
        int c = t + u * 256;        // 512 chunks: (pix 128) x (seg 4)
        int pix = c >> 2, seg = c & 3;
        u16 tmp[8];
#pragma unroll
        for (int e = 0; e < 8; ++e)
            tmp[e] = f2bf(tile[(seg * 8 + e) * 129 + pix]);
        size_t dst = ((size_t)(b * 1024 + pixg * 128 + pix)) * 128
                   + cig * 32 + seg * 8;
        *(ushort4*)&xT[dst]     = make_ushort4(tmp[0], tmp[1], tmp[2], tmp[3]);
        *(ushort4*)&xT[dst + 4] = make_ushort4(tmp[4], tmp[5], tmp[6], tmp[7]);
    }
}

// ---------------------------------------------------------------------------
// conv2: MFMA implicit-GEMM 3x3 conv. grid (4 pixtiles, 16 b, 3 j), 256 thr.
// Block tile: 128 co x 256 pix, K = 9 taps x 128 ci. Wave tile 64co x 128pix.
// Xh: haloed pixel rows [p0-33, p0+289) x 128ci bf16, rotate-swizzled segs.
// W: per-tap 128co x 128ci slab, register-double-buffered.
// ---------------------------------------------------------------------------
__global__ __launch_bounds__(256, 1) void conv2_kernel(
        const u16* __restrict__ xT, const u16* __restrict__ Wt,
        float* __restrict__ conv_out, float* __restrict__ stats) {
    __shared__ __align__(16) u16 Xh[322 * 128];
    __shared__ __align__(16) u16 WL[128 * 128];
    __shared__ float rs[8];

    int t = threadIdx.x;
    int pt = blockIdx.x, b = blockIdx.y, j = blockIdx.z;
    int p0 = pt * 256;
    int w = t >> 6, lane = t & 63;
    int q = lane >> 4, l16 = lane & 15;
    int cobase = (w & 1) * 64, pixbase = (w >> 1) * 128;

    // ---- stage Xh (zero rows for out-of-image pixels) ----
    const u16* xb = xT + (size_t)b * 1024 * 128;
#pragma unroll
    for (int k = 0; k < 21; ++k) {
        int c = t + k * 256;
        if (c < 322 * 16) {
            int row = c >> 4, seg = c & 15;
            int pg = p0 - 33 + row;
            uint4 v = make_uint4(0, 0, 0, 0);
            if (pg >= 0 && pg < 1024)
                v = *(const uint4*)(xb + (size_t)pg * 128 + seg * 8);
            *(uint4*)&Xh[row * 128 + ((seg + row) & 15) * 8] = v;
        }
    }
    // ---- stage W tap 0 ----
    const u16* wjb = Wt + (size_t)j * 9 * 16384;
#pragma unroll
    for (int k = 0; k < 8; ++k) {
        int c = t + k * 256;            // 2048 chunks
        int co = c >> 4, seg = c & 15;
        uint4 v = *(const uint4*)(wjb + co * 128 + seg * 8);
        *(uint4*)&WL[co * 128 + ((seg + co) & 15) * 8] = v;
    }
    __syncthreads();

    f32x4 acc[4][8];
#pragma unroll
    for (int mt = 0; mt < 4; ++mt)
#pragma unroll
        for (int nt = 0; nt < 8; ++nt)
            acc[mt][nt] = (f32x4)0.f;

    uint4 wreg[8];
    for (int tap = 0; tap < 9; ++tap) {
        int dy = tap / 3, dx = tap % 3;
        if (tap < 8) {
            const u16* wn = wjb + (tap + 1) * 16384;
#pragma unroll
            for (int k = 0; k < 8; ++k) {
                int c = t + k * 256;
                wreg[k] = *(const uint4*)(wn + (c >> 4) * 128 + (c & 15) * 8);
            }
        }
        // column zero-pad predicates (flat-shift wrap fix):
        // nt even tiles: xx = l16; nt odd: xx = 16 + l16
        bool inv_e = (dx == 0) && (l16 == 0);
        bool inv_o = (dx == 2) && (l16 == 15);
        int rbase = pixbase + dy * 32 + dx + l16;

#pragma unroll
        for (int ks = 0; ks < 4; ++ks) {
            int sl = ks * 4 + q;        // logical seg
            short8 a[4], bf[8];
#pragma unroll
            for (int mt = 0; mt < 4; ++mt) {
                int row = cobase + mt * 16 + l16;
                a[mt] = *(const short8*)&WL[row * 128 + ((sl + row) & 15) * 8];
            }
#pragma unroll
            for (int nt = 0; nt < 8; ++nt) {
                int row = rbase + nt * 16;
                short8 v = *(const short8*)&Xh[row * 128 + ((sl + row) & 15) * 8];
                if ((nt & 1) ? inv_o : inv_e) v = (short8)0;
                bf[nt] = v;
            }
#pragma unroll
            for (int mt = 0; mt < 4; ++mt)
#pragma unroll
                for (int nt = 0; nt < 8; ++nt)
                    acc[mt][nt] = __builtin_amdgcn_mfma_f32_16x16x32_bf16(
                        a[mt], bf[nt], acc[mt][nt], 0, 0, 0);
        }
        __syncthreads();
        if (tap < 8) {
#pragma unroll
            for (int k = 0; k < 8; ++k) {
                int c = t + k * 256;
                *(uint4*)&WL[(c >> 4) * 128 + (((c & 15) + (c >> 4)) & 15) * 8]
                    = wreg[k];
            }
        }
        __syncthreads();
    }

    // ---- epilogue: write conv_out [j*16+b][co][pix] + stats ----
    float s = 0.f, s2 = 0.f;
    size_t obase = ((size_t)(j * NB + b) * NC) * NPIX;
#pragma unroll
    for (int mt = 0; mt < 4; ++mt) {
#pragma unroll
        for (int nt = 0; nt < 8; ++nt) {
            f32x4 v = acc[mt][nt];
            int co  = cobase + mt * 16 + q * 4;
            int pix = p0 + pixbase + nt * 16 + l16;
#pragma unroll
            for (int r = 0; r < 4; ++r) {
                float val = v[r];
                conv_out[obase + (size_t)(co + r) * NPIX + pix] = val;
                s += val;
                s2 = fmaf(val, val, s2);
            }
        }
    }
#pragma unroll
    for (int off = 32; off; off >>= 1) {
        s  += __shfl_down(s,  (unsigned)off, 64);
        s2 += __shfl_down(s2, (unsigned)off, 64);
    }
    if (lane == 0) { rs[w] = s; rs[4 + w] = s2; }
    __syncthreads();
    if (t == 0) {
        atomicAdd(&stats[(j * NB + b) * 2 + 0], rs[0] + rs[1] + rs[2] + rs[3]);
        atomicAdd(&stats[(j * NB + b) * 2 + 1], rs[4] + rs[5] + rs[6] + rs[7]);
    }
}

// ---------------------------------------------------------------------------
// Kernel 2: GroupNorm(1) + exact GELU + transpose (unchanged from round 3)
// ---------------------------------------------------------------------------
__global__ __launch_bounds__(256) void norm_kernel(
        const float* __restrict__ conv_out, const float* __restrict__ stats,
        const void* __restrict__ g0, const void* __restrict__ b0,
        const void* __restrict__ g1, const void* __restrict__ b1,
        const void* __restrict__ g2, const void* __restrict__ b2,
        float* __restrict__ qkv, const int* __restrict__ flag) {
    __shared__ float tile[32 * 257];
    int isf = flag[0];
    int t = threadIdx.x;
    int n0 = blockIdx.x * 256;
    int h = blockIdx.y;
    int z = blockIdx.z;
    int j = z >> 4;
    const void* gam = (j == 0) ? g0 : ((j == 1) ? g1 : g2);
    const void* bet = (j == 0) ? b0 : ((j == 1) ? b1 : b2);

    float sum = stats[z * 2], ss = stats[z * 2 + 1];
    const float inv = 1.0f / 131072.0f;
    float mean = sum * inv;
    float var  = fmaxf(ss * inv - mean * mean, 0.f);
    float rstd = rsqrtf(var + 1e-6f);

    const float* src = conv_out + ((size_t)z * NC + h * DH) * NPIX + n0;
#pragma unroll
    for (int cl = 0; cl < 32; ++cl) tile[cl * 257 + t] = src[cl * NPIX + t];
    __syncthreads();

    float* dst = qkv + (size_t)z * (NC * NPIX) + h * (NPIX * DH) + n0 * DH;
#pragma unroll
    for (int k = 0; k < 32; ++k) {
        int o = t + k * 256;
        int d = o & 31, nl = o >> 5;
        float v = tile[d * 257 + nl];
        v = (v - mean) * rstd * loadf(gam, h * DH + d, isf)
          + loadf(bet, h * DH + d, isf);
        v = 0.5f * v * (1.0f + erff(v * 0.70710678118654752f));   // exact GELU
        dst[o] = v;
    }
}

// ---------------------------------------------------------------------------
// Kernel 0: bias[h][n][m] (fp32, unchanged from round 3)
// ---------------------------------------------------------------------------
__global__ __launch_bounds__(256) void bias_kernel(
        const int* __restrict__ rel, const void* __restrict__ table,
        float* __restrict__ biasb, const int* __restrict__ flag) {
    int isf = flag[0];
    int i = blockIdx.x * 256 + threadIdx.x;
    if (i >= 4 * 1024 * 1024) return;
    int h  = i >> 20;
    int nm = i & 0xFFFFF;
    int ri = rel[nm];
    biasb[i] = loadf(table, ri * NH + h, isf);
}

// ---------------------------------------------------------------------------
// Kernel 3: flash attention (unchanged from round 3)
// ---------------------------------------------------------------------------
__global__ __launch_bounds__(256) void attn_kernel(
        const float* __restrict__ qkv, const float* __restrict__ biasb,
        float* __restrict__ attf) {
    __shared__ float Qs[64 * 33];
    __shared__ float KT[32 * 64];
    __shared__ float Vs[64 * 32];
    __shared__ float Sb[64 * 65];
    __shared__ float red[4 * 64];
    __shared__ float mrow[64], lrow[64], arow[64];

    int t = threadIdx.x;
    int n0 = blockIdx.x * 64, h = blockIdx.y, b = blockIdx.z;

    size_t qoff = (size_t)b * (NC * NPIX) + h * (NPIX * DH) + n0 * DH;
    {
        const float4* qp = (const float4*)(qkv + qoff);
        float4 a = qp[t * 2], c = qp[t * 2 + 1];
        int f = t * 8, r = f >> 5, d = f & 31;
        float* dst = &Qs[r * 33 + d];
        dst[0] = a.x; dst[1] = a.y; dst[2] = a.z; dst[3] = a.w;
        dst[4] = c.x; dst[5] = c.y; dst[6] = c.z; dst[7] = c.w;
    }
    if (t < 64) { mrow[t] = -1e30f; lrow[t] = 0.f; }

    float o_[8] = {0, 0, 0, 0, 0, 0, 0, 0};
    int r_s = t & 63, mb = t >> 6, m16 = mb * 16;
    int r_o = t >> 2, d0 = (t & 3) * 8;
    __syncthreads();

    for (int kc = 0; kc < 16; ++kc) {
        size_t koff = (size_t)(NB * NC * NPIX) + (size_t)b * (NC * NPIX)
                    + h * (NPIX * DH) + (size_t)(kc * 64) * DH;
        size_t voff = koff + (size_t)(NB * NC * NPIX);
        {
            const float4* kp = (const float4*)(qkv + koff);
            float4 a = kp[t * 2], c = kp[t * 2 + 1];
            int f = t * 8, rr = f >> 5, dd = f & 31;
            KT[(dd + 0) * 64 + rr] = a.x; KT[(dd + 1) * 64 + rr] = a.y;
            KT[(dd + 2) * 64 + rr] = a.z; KT[(dd + 3) * 64 + rr] = a.w;
            KT[(dd + 4) * 64 + rr] = c.x; KT[(dd + 5) * 64 + rr] = c.y;
            KT[(dd + 6) * 64 + rr] = c.z; KT[(dd + 7) * 64 + rr] = c.w;
            const float4* vp = (const float4*)(qkv + voff);
            float4 va = vp[t * 2], vb = vp[t * 2 + 1];
            *(float4*)&Vs[rr * 32 + dd]     = va;
            *(float4*)&Vs[rr * 32 + dd + 4] = vb;
        }
        __syncthreads();

        float sc[16];
        const float* bp = biasb + ((size_t)h << 20) + (size_t)(n0 + r_s) * NPIX
                        + kc * 64 + m16;
#pragma unroll
        for (int i = 0; i < 16; ++i) sc[i] = bp[i];
#pragma unroll 4
        for (int d = 0; d < 32; ++d) {
            float qv = Qs[r_s * 33 + d];
            const float4* kp = (const float4*)&KT[d * 64 + m16];
            float4 k0 = kp[0], k1 = kp[1], k2 = kp[2], k3 = kp[3];
            sc[0]  = fmaf(qv, k0.x, sc[0]);  sc[1]  = fmaf(qv, k0.y, sc[1]);
            sc[2]  = fmaf(qv, k0.z, sc[2]);  sc[3]  = fmaf(qv, k0.w, sc[3]);
            sc[4]  = fmaf(qv, k1.x, sc[4]);  sc[5]  = fmaf(qv, k1.y, sc[5]);
            sc[6]  = fmaf(qv, k1.z, sc[6]);  sc[7]  = fmaf(qv, k1.w, sc[7]);
            sc[8]  = fmaf(qv, k2.x, sc[8]);  sc[9]  = fmaf(qv, k2.y, sc[9]);
            sc[10] = fmaf(qv, k2.z, sc[10]); sc[11] = fmaf(qv, k2.w, sc[11]);
            sc[12] = fmaf(qv, k3.x, sc[12]); sc[13] = fmaf(qv, k3.y, sc[13]);
            sc[14] = fmaf(qv, k3.z, sc[14]); sc[15] = fmaf(qv, k3.w, sc[15]);
        }
        float lm = sc[0];
#pragma unroll
        for (int i = 1; i < 16; ++i) lm = fmaxf(lm, sc[i]);
        red[mb * 64 + r_s] = lm;
        __syncthreads();

        if (t < 64) {
            float mo = mrow[t];
            float mn = fmaxf(mo, fmaxf(fmaxf(red[t], red[64 + t]),
                                       fmaxf(red[128 + t], red[192 + t])));
            mrow[t] = mn;
            arow[t] = __expf(mo - mn);
        }
        __syncthreads();

        float mn = mrow[r_s];
        float ps = 0.f;
#pragma unroll
        for (int i = 0; i < 16; ++i) {
            float p = __expf(sc[i] - mn);
            Sb[r_s * 65 + m16 + i] = p;
            ps += p;
        }
        red[mb * 64 + r_s] = ps;
        __syncthreads();

        if (t < 64)
            lrow[t] = lrow[t] * arow[t] + red[t] + red[64 + t]
                    + red[128 + t] + red[192 + t];

        float al = arow[r_o];
#pragma unroll
        for (int i = 0; i < 8; ++i) o_[i] *= al;
#pragma unroll 4
        for (int m = 0; m < 64; ++m) {
            float p = Sb[r_o * 65 + m];
            const float4* vp = (const float4*)&Vs[m * 32 + d0];
            float4 va = vp[0], vb = vp[1];
            o_[0] = fmaf(p, va.x, o_[0]); o_[1] = fmaf(p, va.y, o_[1]);
            o_[2] = fmaf(p, va.z, o_[2]); o_[3] = fmaf(p, va.w, o_[3]);
            o_[4] = fmaf(p, vb.x, o_[4]); o_[5] = fmaf(p, vb.y, o_[5]);
            o_[6] = fmaf(p, vb.z, o_[6]); o_[7] = fmaf(p, vb.w, o_[7]);
        }
        __syncthreads();
    }

    float rl = 1.0f / lrow[r_o];
    size_t ooff = ((size_t)b * NPIX + n0 + r_o) * NC + h * DH + d0;
    *(float4*)(attf + ooff) =
        make_float4(o_[0] * rl, o_[1] * rl, o_[2] * rl, o_[3] * rl);
    *(float4*)(attf + ooff + 4) =
        make_float4(o_[4] * rl, o_[5] * rl, o_[6] * rl, o_[7] * rl);
}

// ---------------------------------------------------------------------------
// Kernel 4: 1x1 conv + bias (unchanged from round 3)
// ---------------------------------------------------------------------------
__global__ __launch_bounds__(256) void out_kernel(
        const float* __restrict__ attf, const void* __restrict__ ow,
        const void* __restrict__ ob, void* __restrict__ out,
        const int* __restrict__ flag) {
    __shared__ float aL[32 * 129];
    __shared__ float wL[128 * 128];
    int isf = flag[0];
    int t = threadIdx.x;
    int n0 = blockIdx.x * 32, b = blockIdx.y;

    const float4* ap = (const float4*)(attf + ((size_t)b * NPIX + n0) * NC);
#pragma unroll
    for (int k = 0; k < 4; ++k) {
        int fi = t + k * 256;
        float4 v = ap[fi];
        int fl = fi * 4, rw = fl >> 7, cl = fl & 127;
        float* dst = &aL[rw * 129 + cl];
        dst[0] = v.x; dst[1] = v.y; dst[2] = v.z; dst[3] = v.w;
    }
    for (int i = t; i < 128 * 128; i += 256) wL[i] = loadf(ow, i, isf);
    __syncthreads();

    int nl = t & 31, cg = t >> 5;
    const float* arow_ = &aL[nl * 129];
#pragma unroll
    for (int k = 0; k < 16; ++k) {
        int co = cg * 16 + k;
        const float* wr = &wL[co * 128];
        float acc = loadf(ob, co, isf);
#pragma unroll 16
        for (int ci = 0; ci < 128; ++ci)
            acc = fmaf(wr[ci], arow_[ci], acc);
        size_t oidx = ((size_t)b * NC + co) * NPIX + n0 + nl;
        if (isf) ((float*)out)[oidx] = acc;
        else     ((u16*)out)[oidx]   = f2bf(acc);
    }
}

// ---------------------------------------------------------------------------
// Workspace (peak ~48 MiB, lifetime aliasing):
//   [0,448)   stats | [448,452) flag
//   [512, +25165824)  region Q:
//       xT  bf16 (8,388,608 B) at Q+0       (prep_x -> conv2)
//       Wt  bf16 (  884,736 B) at Q+8388608 (prep_w -> conv2)
//       then qkv fp32 (25,165,824 B) at Q   (norm -> attn; overwrites xT/Wt)
//   [A, +25165824) region A2 (A = 512+25165824):
//       conv fp32 (25,165,824 B)            (conv2 -> norm)
//       then biasb fp32 (16 MB) at A2, attf fp32 (8 MB) at A2+16MB
// Order: memset -> detect -> prep_w -> prep_x -> conv2 -> norm -> bias ->
//        attn -> out
// ---------------------------------------------------------------------------
extern "C" void kernel_launch(void* const* d_in, const int* in_sizes, int n_in,
                              void* d_out, int out_size, void* d_ws,
                              size_t ws_size, hipStream_t stream) {
    (void)in_sizes; (void)n_in; (void)out_size; (void)ws_size;
    const void* x     = d_in[0];
    const void* wq    = d_in[1];
    const void* gq    = d_in[2];
    const void* bq    = d_in[3];
    const void* wk    = d_in[4];
    const void* gk    = d_in[5];
    const void* bk    = d_in[6];
    const void* wv    = d_in[7];
    const void* gv    = d_in[8];
    const void* bv    = d_in[9];
    const void* table = d_in[10];
    const int*  rel   = (const int*)d_in[11];
    const void* ow    = d_in[12];
    const void* ob    = d_in[13];

    char* ws = (char*)d_ws;
    float* stats = (float*)(ws);
    int*   flag  = (int*)(ws + 448);
    char*  regQ  = ws + 512;
    u16*   xT    = (u16*)regQ;                       // prep_x -> conv2
    u16*   Wt    = (u16*)(regQ + 8388608);           // prep_w -> conv2
    float* qkv   = (float*)regQ;                     // norm -> attn (aliases)
    char*  regA  = ws + 512 + 25165824;
    float* conv  = (float*)regA;                     // conv2 -> norm
    float* biasb = (float*)regA;                     // bias -> attn (alias)
    float* attf  = (float*)(regA + 16777216);        // attn -> out  (alias)

    hipMemsetAsync(stats, 0, 96 * sizeof(float), stream);
    detect_kernel<<<1, 256, 0, stream>>>(x, flag);
    prep_w<<<1728, 256, 0, stream>>>(wq, wk, wv, Wt, flag);
    prep_x<<<dim3(8, 4, 16), 256, 0, stream>>>(x, xT, flag);
    conv2_kernel<<<dim3(4, 16, 3), 256, 0, stream>>>(xT, Wt, conv, stats);
    norm_kernel<<<dim3(4, 4, 48), 256, 0, stream>>>(conv, stats,
                                                    gq, bq, gk, bk, gv, bv,
                                                    qkv, flag);
    bias_kernel<<<16384, 256, 0, stream>>>(rel, table, biasb, flag);
    attn_kernel<<<dim3(16, 4, 16), 256, 0, stream>>>(qkv, biasb, attf);
    out_kernel<<<dim3(32, 16), 256, 0, stream>>>(attf, ow, ob, d_out, flag);
}

// Round 7
// 277.356 us; speedup vs baseline: 2.6666x; 1.5085x over previous
//
#include <hip/hip_runtime.h>

typedef unsigned short u16;
typedef unsigned int   u32;

#define NB   16      // batch
#define NC   128     // channels
#define NPIX 1024    // 32*32
#define NH   4       // heads
#define DH   32      // dim head

typedef __attribute__((ext_vector_type(8))) short short8;
typedef __attribute__((ext_vector_type(4))) float f32x4;
typedef __attribute__((ext_vector_type(8))) _Float16 half8;

__device__ __forceinline__ float bf2f(u16 u) {
    return __uint_as_float(((u32)u) << 16);
}
__device__ __forceinline__ u16 f2bf(float f) {
    u32 u = __float_as_uint(f);
    u32 r = (u + 0x7fffu + ((u >> 16) & 1u)) >> 16;
    return (u16)r;
}
__device__ __forceinline__ u16 f2h(float f) {
    _Float16 h = (_Float16)f;
    u16 r; __builtin_memcpy(&r, &h, 2); return r;
}
__device__ __forceinline__ int pk_h2(float a, float b) {
    auto h = __builtin_amdgcn_cvt_pkrtz(a, b);   // __fp16 ext_vector(2)
    int r; __builtin_memcpy(&r, &h, 4); return r;
}
// dtype-agnostic loads: isf=1 -> fp32 data, isf=0 -> bf16 data
__device__ __forceinline__ float loadf(const void* p, int i, int isf) {
    return isf ? ((const float*)p)[i] : bf2f(((const u16*)p)[i]);
}
__device__ __forceinline__ float4 load4(const void* p, int i4, int isf) {
    if (isf) return ((const float4*)p)[i4];
    ushort4 u = ((const ushort4*)p)[i4];
    return make_float4(bf2f(u.x), bf2f(u.y), bf2f(u.z), bf2f(u.w));
}

// ---------------------------------------------------------------------------
// Kernel D: dtype detector (proven).
// ---------------------------------------------------------------------------
__global__ __launch_bounds__(256) void detect_kernel(
        const void* __restrict__ x, int* __restrict__ flag) {
    __shared__ int cnt;
    if (threadIdx.x == 0) cnt = 0;
    __syncthreads();
    const u16* p = (const u16*)x;
    int c = 0;
    for (int i = threadIdx.x; i < 4096; i += 256) {
        int e = (p[i] >> 7) & 0xFF;
        if (e >= 134) ++c;
    }
    atomicAdd(&cnt, c);
    __syncthreads();
    if (threadIdx.x == 0) flag[0] = (cnt > 100) ? 1 : 0;
}

// ---------------------------------------------------------------------------
// prep_w: Wt[j][tap][co][ci] bf16 from w_j OIHW (proven)
// ---------------------------------------------------------------------------
__global__ __launch_bounds__(256) void prep_w(
        const void* __restrict__ w0, const void* __restrict__ w1,
        const void* __restrict__ w2, u16* __restrict__ Wt,
        const int* __restrict__ flag) {
    int isf = flag[0];
    int i = blockIdx.x * 256 + threadIdx.x;
    if (i >= 442368) return;
    int j   = i / 147456;
    int rr  = i % 147456;
    int tap = rr >> 14;
    int co  = (rr >> 7) & 127;
    int ci  = rr & 127;
    const void* w = (j == 0) ? w0 : ((j == 1) ? w1 : w2);
    float v = loadf(w, (co * 128 + ci) * 9 + tap, isf);
    Wt[i] = f2bf(v);
}

// ---------------------------------------------------------------------------
// prep_x: xT[b][pix][ci] bf16 from x[b][ci][pix] (proven)
// ---------------------------------------------------------------------------
__global__ __launch_bounds__(256) void prep_x(
        const void* __restrict__ x, u16* __restrict__ xT,
        const int* __restrict__ flag) {
    __shared__ float tile[32 * 129];
    int isf = flag[0];
    int t = threadIdx.x;
    int pixg = blockIdx.x, cig = blockIdx.y, b = blockIdx.z;

    int ci = t >> 3, px0 = (t & 7) * 16;
    int base = b * (NC * NPIX) + (cig * 32 + ci) * NPIX + pixg * 128 + px0;
#pragma unroll
    for (int u = 0; u < 4; ++u) {
        float4 v = load4(x, (base >> 2) + u, isf);
        float* d = &tile[ci * 129 + px0 + u * 4];
        d[0] = v.x; d[1] = v.y; d[2] = v.z; d[3] = v.w;
    }
    __syncthreads();
#pragma unroll
    for (int u = 0; u < 2; ++u) {
        int c = t + u * 256;
        int pix = c >> 2, seg = c & 3;
        u16 tmp[8];
#pragma unroll
        for (int e = 0; e < 8; ++e)
            tmp[e] = f2bf(tile[(seg * 8 + e) * 129 + pix]);
        size_t dst = ((size_t)(b * 1024 + pixg * 128 + pix)) * 128
                   + cig * 32 + seg * 8;
        *(ushort4*)&xT[dst]     = make_ushort4(tmp[0], tmp[1], tmp[2], tmp[3]);
        *(ushort4*)&xT[dst + 4] = make_ushort4(tmp[4], tmp[5], tmp[6], tmp[7]);
    }
}

// ---------------------------------------------------------------------------
// conv2: MFMA implicit-GEMM 3x3 conv (proven in round 4)
// ---------------------------------------------------------------------------
__global__ __launch_bounds__(256, 1) void conv2_kernel(
        const u16* __restrict__ xT, const u16* __restrict__ Wt,
        float* __restrict__ conv_out, float* __restrict__ stats) {
    __shared__ __align__(16) u16 Xh[322 * 128];
    __shared__ __align__(16) u16 WL[128 * 128];
    __shared__ float rs[8];

    int t = threadIdx.x;
    int pt = blockIdx.x, b = blockIdx.y, j = blockIdx.z;
    int p0 = pt * 256;
    int w = t >> 6, lane = t & 63;
    int q = lane >> 4, l16 = lane & 15;
    int cobase = (w & 1) * 64, pixbase = (w >> 1) * 128;

    const u16* xb = xT + (size_t)b * 1024 * 128;
#pragma unroll
    for (int k = 0; k < 21; ++k) {
        int c = t + k * 256;
        if (c < 322 * 16) {
            int row = c >> 4, seg = c & 15;
            int pg = p0 - 33 + row;
            uint4 v = make_uint4(0, 0, 0, 0);
            if (pg >= 0 && pg < 1024)
                v = *(const uint4*)(xb + (size_t)pg * 128 + seg * 8);
            *(uint4*)&Xh[row * 128 + ((seg + row) & 15) * 8] = v;
        }
    }
    const u16* wjb = Wt + (size_t)j * 9 * 16384;
#pragma unroll
    for (int k = 0; k < 8; ++k) {
        int c = t + k * 256;
        int co = c >> 4, seg = c & 15;
        uint4 v = *(const uint4*)(wjb + co * 128 + seg * 8);
        *(uint4*)&WL[co * 128 + ((seg + co) & 15) * 8] = v;
    }
    __syncthreads();

    f32x4 acc[4][8];
#pragma unroll
    for (int mt = 0; mt < 4; ++mt)
#pragma unroll
        for (int nt = 0; nt < 8; ++nt)
            acc[mt][nt] = (f32x4)0.f;

    uint4 wreg[8];
    for (int tap = 0; tap < 9; ++tap) {
        int dy = tap / 3, dx = tap % 3;
        if (tap < 8) {
            const u16* wn = wjb + (tap + 1) * 16384;
#pragma unroll
            for (int k = 0; k < 8; ++k) {
                int c = t + k * 256;
                wreg[k] = *(const uint4*)(wn + (c >> 4) * 128 + (c & 15) * 8);
            }
        }
        bool inv_e = (dx == 0) && (l16 == 0);
        bool inv_o = (dx == 2) && (l16 == 15);
        int rbase = pixbase + dy * 32 + dx + l16;

#pragma unroll
        for (int ks = 0; ks < 4; ++ks) {
            int sl = ks * 4 + q;
            short8 a[4], bf[8];
#pragma unroll
            for (int mt = 0; mt < 4; ++mt) {
                int row = cobase + mt * 16 + l16;
                a[mt] = *(const short8*)&WL[row * 128 + ((sl + row) & 15) * 8];
            }
#pragma unroll
            for (int nt = 0; nt < 8; ++nt) {
                int row = rbase + nt * 16;
                short8 v = *(const short8*)&Xh[row * 128 + ((sl + row) & 15) * 8];
                if ((nt & 1) ? inv_o : inv_e) v = (short8)0;
                bf[nt] = v;
            }
#pragma unroll
            for (int mt = 0; mt < 4; ++mt)
#pragma unroll
                for (int nt = 0; nt < 8; ++nt)
                    acc[mt][nt] = __builtin_amdgcn_mfma_f32_16x16x32_bf16(
                        a[mt], bf[nt], acc[mt][nt], 0, 0, 0);
        }
        __syncthreads();
        if (tap < 8) {
#pragma unroll
            for (int k = 0; k < 8; ++k) {
                int c = t + k * 256;
                *(uint4*)&WL[(c >> 4) * 128 + (((c & 15) + (c >> 4)) & 15) * 8]
                    = wreg[k];
            }
        }
        __syncthreads();
    }

    float s = 0.f, s2 = 0.f;
    size_t obase = ((size_t)(j * NB + b) * NC) * NPIX;
#pragma unroll
    for (int mt = 0; mt < 4; ++mt) {
#pragma unroll
        for (int nt = 0; nt < 8; ++nt) {
            f32x4 v = acc[mt][nt];
            int co  = cobase + mt * 16 + q * 4;
            int pix = p0 + pixbase + nt * 16 + l16;
#pragma unroll
            for (int r = 0; r < 4; ++r) {
                float val = v[r];
                conv_out[obase + (size_t)(co + r) * NPIX + pix] = val;
                s += val;
                s2 = fmaf(val, val, s2);
            }
        }
    }
#pragma unroll
    for (int off = 32; off; off >>= 1) {
        s  += __shfl_down(s,  (unsigned)off, 64);
        s2 += __shfl_down(s2, (unsigned)off, 64);
    }
    if (lane == 0) { rs[w] = s; rs[4 + w] = s2; }
    __syncthreads();
    if (t == 0) {
        atomicAdd(&stats[(j * NB + b) * 2 + 0], rs[0] + rs[1] + rs[2] + rs[3]);
        atomicAdd(&stats[(j * NB + b) * 2 + 1], rs[4] + rs[5] + rs[6] + rs[7]);
    }
}

// ---------------------------------------------------------------------------
// norm_kernel: GroupNorm(1) + exact GELU. Outputs f16:
//   j=0 -> qh [b][h][n][32], j=1 -> kh [b][h][n][32], j=2 -> vh [b][h][32][n]
// grid (4 ntiles, 4 h, 48 z=j*16+b), block 256
// ---------------------------------------------------------------------------
__global__ __launch_bounds__(256) void norm_kernel(
        const float* __restrict__ conv_out, const float* __restrict__ stats,
        const void* __restrict__ g0, const void* __restrict__ b0,
        const void* __restrict__ g1, const void* __restrict__ b1,
        const void* __restrict__ g2, const void* __restrict__ b2,
        u16* __restrict__ qh, u16* __restrict__ kh, u16* __restrict__ vh,
        const int* __restrict__ flag) {
    __shared__ float tile[32 * 257];
    int isf = flag[0];
    int t = threadIdx.x;
    int n0 = blockIdx.x * 256;
    int h = blockIdx.y;
    int z = blockIdx.z;
    int j = z >> 4;
    int b = z & 15;
    const void* gam = (j == 0) ? g0 : ((j == 1) ? g1 : g2);
    const void* bet = (j == 0) ? b0 : ((j == 1) ? b1 : b2);

    float sum = stats[z * 2], ss = stats[z * 2 + 1];
    const float inv = 1.0f / 131072.0f;
    float mean = sum * inv;
    float var  = fmaxf(ss * inv - mean * mean, 0.f);
    float rstd = rsqrtf(var + 1e-6f);

    const float* src = conv_out + ((size_t)z * NC + h * DH) * NPIX + n0;

    if (j == 2) {
        // v: [b][h][d][n] layout — no transpose needed
        u16* dst = vh + (((size_t)(b * NH + h)) * DH) * NPIX + n0;
#pragma unroll
        for (int cl = 0; cl < 32; ++cl) {
            float v = src[cl * NPIX + t];
            v = (v - mean) * rstd * loadf(gam, h * DH + cl, isf)
              + loadf(bet, h * DH + cl, isf);
            v = 0.5f * v * (1.0f + erff(v * 0.70710678118654752f));
            dst[(size_t)cl * NPIX + t] = f2h(v);
        }
        return;
    }

#pragma unroll
    for (int cl = 0; cl < 32; ++cl) tile[cl * 257 + t] = src[cl * NPIX + t];
    __syncthreads();

    u16* dst = ((j == 0) ? qh : kh)
             + (((size_t)(b * NH + h)) * NPIX + n0) * DH;
#pragma unroll
    for (int k = 0; k < 32; ++k) {
        int o = t + k * 256;
        int d = o & 31, nl = o >> 5;
        float v = tile[d * 257 + nl];
        v = (v - mean) * rstd * loadf(gam, h * DH + d, isf)
          + loadf(bet, h * DH + d, isf);
        v = 0.5f * v * (1.0f + erff(v * 0.70710678118654752f));
        dst[o] = f2h(v);
    }
}

// ---------------------------------------------------------------------------
// bias_t kernel: biasT[h][m][n] = table[rel[n*1024+m]][h]  (bf16)
// grid (16 n-tiles, 16 m-tiles), block 256. LDS transpose of rel tile.
// ---------------------------------------------------------------------------
__global__ __launch_bounds__(256) void biasT_kernel(
        const int* __restrict__ rel, const void* __restrict__ table,
        u16* __restrict__ biasT, const int* __restrict__ flag) {
    __shared__ int rl[64 * 65];
    int isf = flag[0];
    int t = threadIdx.x;
    int nt = blockIdx.x, mt = blockIdx.y;

#pragma unroll
    for (int c = 0; c < 16; ++c) {
        int i = t + c * 256;              // 4096
        int r = i >> 6, cc = i & 63;      // r=n-local, cc=m-local
        rl[r * 65 + cc] = rel[(size_t)(nt * 64 + r) * 1024 + mt * 64 + cc];
    }
    __syncthreads();

#pragma unroll
    for (int h = 0; h < NH; ++h) {
#pragma unroll
        for (int c = 0; c < 16; ++c) {
            int wdx = t + c * 256;        // 4096
            int m = wdx >> 6, n = wdx & 63;
            int ri = rl[n * 65 + m];
            float v = loadf(table, ri * NH + h, isf);
            biasT[((size_t)h << 20) + (size_t)(mt * 64 + m) * 1024
                  + nt * 64 + n] = f2bf(v);
        }
    }
}

// ---------------------------------------------------------------------------
// attn2: MFMA flash attention, zero LDS.
// grid (16 b, 4 h, 8 qt), block 256 (4 waves x 32 q-rows).
// qh,kh: f16 [b][h][n][32]; vh: f16 [b][h][32][n]; biasT bf16 [h][m][n].
// S^T = K·Q^T per 16x16 tile (one K=32 mfma), online softmax on C-layout
// (n=lane&15 -> stats via 2 shfl_xor), P^T->B-frag via FULL-EXEC ds_bpermute
// pairs + cndmask select (divergent-ternary bpermute pulls from inactive
// lanes = undefined — round-6 bug), O^T = V^T·P^T in C-layout.
// ---------------------------------------------------------------------------
__global__ __launch_bounds__(256) void attn2_kernel(
        const u16* __restrict__ qh, const u16* __restrict__ kh,
        const u16* __restrict__ vh, const u16* __restrict__ biasT,
        float* __restrict__ attf) {
    int t = threadIdx.x;
    int b = blockIdx.x, h = blockIdx.y, qt = blockIdx.z;
    int w = t >> 6, lane = t & 63, q = lane >> 4, l16 = lane & 15;
    int nrow0 = qt * 128 + w * 32;

    const u16* qb = qh + (((size_t)(b * NH + h)) * NPIX) * DH;
    const u16* kb = kh + (((size_t)(b * NH + h)) * NPIX) * DH;
    const u16* vb = vh + (((size_t)(b * NH + h)) * DH) * NPIX;
    const u16* bb = biasT + ((size_t)h << 20);

    // Q B-frags (held all kernel)
    half8 qf[2];
#pragma unroll
    for (int nt = 0; nt < 2; ++nt)
        qf[nt] = *(const half8*)(qb + (size_t)(nrow0 + nt * 16 + l16) * DH
                                 + q * 8);

    f32x4 O[2][2];   // [dt][nt], O^T C-layout: col n=l16, row d=q*4+reg
#pragma unroll
    for (int dt = 0; dt < 2; ++dt)
#pragma unroll
        for (int nt = 0; nt < 2; ++nt) O[dt][nt] = (f32x4)0.f;
    float mrow[2] = {-1e30f, -1e30f}, lrow[2] = {0.f, 0.f};

    int addrLo = ((2 * (q & 1)) * 16 + l16) * 4;
    int addrHi = addrLo + 64;
    bool hiQ = (q >= 2);

    for (int kc = 0; kc < 8; ++kc) {
        int m0 = kc * 128;
        // ---- S^T tiles: St[mt][nt], C-layout (m=q*4+reg, n=l16) ----
        f32x4 St[8][2];
#pragma unroll
        for (int mt = 0; mt < 8; ++mt) {
            half8 kf = *(const half8*)(kb + (size_t)(m0 + mt * 16 + l16) * DH
                                       + q * 8);
            St[mt][0] = __builtin_amdgcn_mfma_f32_16x16x32_f16(
                kf, qf[0], (f32x4)0.f, 0, 0, 0);
            St[mt][1] = __builtin_amdgcn_mfma_f32_16x16x32_f16(
                kf, qf[1], (f32x4)0.f, 0, 0, 0);
        }
        // ---- bias add + row max ----
        float mx[2] = {-1e30f, -1e30f};
#pragma unroll
        for (int mt = 0; mt < 8; ++mt)
#pragma unroll
            for (int nt = 0; nt < 2; ++nt) {
                const u16* bp = bb + (size_t)(m0 + mt * 16 + q * 4) * 1024
                              + nrow0 + nt * 16 + l16;
#pragma unroll
                for (int r = 0; r < 4; ++r) {
                    float v = St[mt][nt][r] + bf2f(bp[(size_t)r * 1024]);
                    St[mt][nt][r] = v;
                    mx[nt] = fmaxf(mx[nt], v);
                }
            }
        float alpha[2];
#pragma unroll
        for (int nt = 0; nt < 2; ++nt) {
            mx[nt] = fmaxf(mx[nt], __shfl_xor(mx[nt], 16, 64));
            mx[nt] = fmaxf(mx[nt], __shfl_xor(mx[nt], 32, 64));
            float mn = fmaxf(mrow[nt], mx[nt]);
            alpha[nt] = __expf(mrow[nt] - mn);
            mrow[nt] = mn;
        }
        // ---- exp + row sums ----
        float sm[2] = {0.f, 0.f};
#pragma unroll
        for (int mt = 0; mt < 8; ++mt)
#pragma unroll
            for (int nt = 0; nt < 2; ++nt)
#pragma unroll
                for (int r = 0; r < 4; ++r) {
                    float p = __expf(St[mt][nt][r] - mrow[nt]);
                    St[mt][nt][r] = p;
                    sm[nt] += p;
                }
#pragma unroll
        for (int nt = 0; nt < 2; ++nt) {
            sm[nt] += __shfl_xor(sm[nt], 16, 64);
            sm[nt] += __shfl_xor(sm[nt], 32, 64);
            lrow[nt] = lrow[nt] * alpha[nt] + sm[nt];
        }
        // ---- O rescale ----
#pragma unroll
        for (int dt = 0; dt < 2; ++dt)
#pragma unroll
            for (int nt = 0; nt < 2; ++nt)
#pragma unroll
                for (int r = 0; r < 4; ++r)
                    O[dt][nt][r] *= alpha[nt];
        // ---- PV: 4 m-steps of 32 ----
#pragma unroll
        for (int ms = 0; ms < 4; ++ms) {
            half8 vf[2];
#pragma unroll
            for (int dt = 0; dt < 2; ++dt)
                vf[dt] = *(const half8*)(vb + (size_t)(dt * 16 + l16) * NPIX
                                         + m0 + ms * 32 + q * 8);
#pragma unroll
            for (int nt = 0; nt < 2; ++nt) {
                // pack own C-regs to f16 pairs (both source tiles)
                int p01_0 = pk_h2(St[2 * ms][nt][0],     St[2 * ms][nt][1]);
                int p23_0 = pk_h2(St[2 * ms][nt][2],     St[2 * ms][nt][3]);
                int p01_1 = pk_h2(St[2 * ms + 1][nt][0], St[2 * ms + 1][nt][1]);
                int p23_1 = pk_h2(St[2 * ms + 1][nt][2], St[2 * ms + 1][nt][3]);
                // FULL-EXEC bpermutes (both payloads), then per-dest select.
                int a0 = __builtin_amdgcn_ds_bpermute(addrLo, p01_0);
                int a1 = __builtin_amdgcn_ds_bpermute(addrLo, p23_0);
                int a2 = __builtin_amdgcn_ds_bpermute(addrHi, p01_0);
                int a3 = __builtin_amdgcn_ds_bpermute(addrHi, p23_0);
                int b0 = __builtin_amdgcn_ds_bpermute(addrLo, p01_1);
                int b1 = __builtin_amdgcn_ds_bpermute(addrLo, p23_1);
                int b2 = __builtin_amdgcn_ds_bpermute(addrHi, p01_1);
                int b3 = __builtin_amdgcn_ds_bpermute(addrHi, p23_1);
                int pb[4];
                pb[0] = hiQ ? b0 : a0;
                pb[1] = hiQ ? b1 : a1;
                pb[2] = hiQ ? b2 : a2;
                pb[3] = hiQ ? b3 : a3;
                half8 pf; __builtin_memcpy(&pf, pb, 16);
#pragma unroll
                for (int dt = 0; dt < 2; ++dt)
                    O[dt][nt] = __builtin_amdgcn_mfma_f32_16x16x32_f16(
                        vf[dt], pf, O[dt][nt], 0, 0, 0);
            }
        }
    }

    // ---- epilogue: attf[b][n][c] fp32 ----
#pragma unroll
    for (int nt = 0; nt < 2; ++nt) {
        float rl = 1.0f / lrow[nt];
        int n = nrow0 + nt * 16 + l16;
#pragma unroll
        for (int dt = 0; dt < 2; ++dt) {
            f32x4 o = O[dt][nt];
            *(float4*)(attf + ((size_t)b * NPIX + n) * NC + h * DH
                       + dt * 16 + q * 4) =
                make_float4(o[0] * rl, o[1] * rl, o[2] * rl, o[3] * rl);
        }
    }
}

// ---------------------------------------------------------------------------
// Kernel 4: 1x1 conv + bias (unchanged)
// ---------------------------------------------------------------------------
__global__ __launch_bounds__(256) void out_kernel(
        const float* __restrict__ attf, const void* __restrict__ ow,
        const void* __restrict__ ob, void* __restrict__ out,
        const int* __restrict__ flag) {
    __shared__ float aL[32 * 129];
    __shared__ float wL[128 * 128];
    int isf = flag[0];
    int t = threadIdx.x;
    int n0 = blockIdx.x * 32, b = blockIdx.y;

    const float4* ap = (const float4*)(attf + ((size_t)b * NPIX + n0) * NC);
#pragma unroll
    for (int k = 0; k < 4; ++k) {
        int fi = t + k * 256;
        float4 v = ap[fi];
        int fl = fi * 4, rw = fl >> 7, cl = fl & 127;
        float* dst = &aL[rw * 129 + cl];
        dst[0] = v.x; dst[1] = v.y; dst[2] = v.z; dst[3] = v.w;
    }
    for (int i = t; i < 128 * 128; i += 256) wL[i] = loadf(ow, i, isf);
    __syncthreads();

    int nl = t & 31, cg = t >> 5;
    const float* arow_ = &aL[nl * 129];
#pragma unroll
    for (int k = 0; k < 16; ++k) {
        int co = cg * 16 + k;
        const float* wr = &wL[co * 128];
        float acc = loadf(ob, co, isf);
#pragma unroll 16
        for (int ci = 0; ci < 128; ++ci)
            acc = fmaf(wr[ci], arow_[ci], acc);
        size_t oidx = ((size_t)b * NC + co) * NPIX + n0 + nl;
        if (isf) ((float*)out)[oidx] = acc;
        else     ((u16*)out)[oidx]   = f2bf(acc);
    }
}

// ---------------------------------------------------------------------------
// Workspace (peak ~48 MiB, lifetime aliasing):
//   [0,448) stats | [448,452) flag
//   regQ = ws+512 (25,165,824 B):
//     xT bf16 8 MB @Q+0, Wt bf16 0.9 MB @Q+8388608   (prep -> conv2)
//     then qh f16 4 MB @Q+0, kh @Q+4M, vh @Q+8M      (norm -> attn2)
//   regA = regQ+25165824 (25,165,824 B):
//     conv fp32 25 MB                                 (conv2 -> norm)
//     then biasT bf16 8 MB @A+0, attf fp32 8 MB @A+8388608
// Order: memset -> detect -> prep_w -> prep_x -> conv2 -> norm -> biasT ->
//        attn2 -> out
// ---------------------------------------------------------------------------
extern "C" void kernel_launch(void* const* d_in, const int* in_sizes, int n_in,
                              void* d_out, int out_size, void* d_ws,
                              size_t ws_size, hipStream_t stream) {
    (void)in_sizes; (void)n_in; (void)out_size; (void)ws_size;
    const void* x     = d_in[0];
    const void* wq    = d_in[1];
    const void* gq    = d_in[2];
    const void* bq    = d_in[3];
    const void* wk    = d_in[4];
    const void* gk    = d_in[5];
    const void* bk    = d_in[6];
    const void* wv    = d_in[7];
    const void* gv    = d_in[8];
    const void* bv    = d_in[9];
    const void* table = d_in[10];
    const int*  rel   = (const int*)d_in[11];
    const void* ow    = d_in[12];
    const void* ob    = d_in[13];

    char* ws = (char*)d_ws;
    float* stats = (float*)(ws);
    int*   flag  = (int*)(ws + 448);
    char*  regQ  = ws + 512;
    u16*   xT    = (u16*)regQ;
    u16*   Wt    = (u16*)(regQ + 8388608);
    u16*   qhp   = (u16*)regQ;                       // alias after conv2
    u16*   khp   = (u16*)(regQ + 4194304);
    u16*   vhp   = (u16*)(regQ + 8388608);
    char*  regA  = regQ + 25165824;
    float* conv  = (float*)regA;                     // conv2 -> norm
    u16*   biasT = (u16*)regA;                       // alias after norm
    float* attf  = (float*)(regA + 8388608);

    (void)hipMemsetAsync(stats, 0, 96 * sizeof(float), stream);
    detect_kernel<<<1, 256, 0, stream>>>(x, flag);
    prep_w<<<1728, 256, 0, stream>>>(wq, wk, wv, Wt, flag);
    prep_x<<<dim3(8, 4, 16), 256, 0, stream>>>(x, xT, flag);
    conv2_kernel<<<dim3(4, 16, 3), 256, 0, stream>>>(xT, Wt, conv, stats);
    norm_kernel<<<dim3(4, 4, 48), 256, 0, stream>>>(conv, stats,
                                                    gq, bq, gk, bk, gv, bv,
                                                    qhp, khp, vhp, flag);
    biasT_kernel<<<dim3(16, 16), 256, 0, stream>>>(rel, table, biasT, flag);
    attn2_kernel<<<dim3(16, 4, 8), 256, 0, stream>>>(qhp, khp, vhp, biasT,
                                                     attf);
    out_kernel<<<dim3(32, 16), 256, 0, stream>>>(attf, ow, ob, d_out, flag);
}

// Round 8
// 230.643 us; speedup vs baseline: 3.2066x; 1.2025x over previous
//
#include <hip/hip_runtime.h>

typedef unsigned short u16;
typedef unsigned int   u32;

#define NB   16      // batch
#define NC   128     // channels
#define NPIX 1024    // 32*32
#define NH   4       // heads
#define DH   32      // dim head

typedef __attribute__((ext_vector_type(8))) short short8;
typedef __attribute__((ext_vector_type(4))) float f32x4;
typedef __attribute__((ext_vector_type(8))) _Float16 half8;

__device__ __forceinline__ float bf2f(u16 u) {
    return __uint_as_float(((u32)u) << 16);
}
__device__ __forceinline__ u16 f2bf(float f) {
    u32 u = __float_as_uint(f);
    u32 r = (u + 0x7fffu + ((u >> 16) & 1u)) >> 16;
    return (u16)r;
}
__device__ __forceinline__ u16 f2h(float f) {
    _Float16 h = (_Float16)f;
    u16 r; __builtin_memcpy(&r, &h, 2); return r;
}
__device__ __forceinline__ int pk_h2(float a, float b) {
    auto h = __builtin_amdgcn_cvt_pkrtz(a, b);   // __fp16 ext_vector(2)
    int r; __builtin_memcpy(&r, &h, 4); return r;
}
// dtype-agnostic loads: isf=1 -> fp32 data, isf=0 -> bf16 data
__device__ __forceinline__ float loadf(const void* p, int i, int isf) {
    return isf ? ((const float*)p)[i] : bf2f(((const u16*)p)[i]);
}
__device__ __forceinline__ float4 load4(const void* p, int i4, int isf) {
    if (isf) return ((const float4*)p)[i4];
    ushort4 u = ((const ushort4*)p)[i4];
    return make_float4(bf2f(u.x), bf2f(u.y), bf2f(u.z), bf2f(u.w));
}

// ---------------------------------------------------------------------------
// Kernel D: dtype detector (proven).
// ---------------------------------------------------------------------------
__global__ __launch_bounds__(256) void detect_kernel(
        const void* __restrict__ x, int* __restrict__ flag) {
    __shared__ int cnt;
    if (threadIdx.x == 0) cnt = 0;
    __syncthreads();
    const u16* p = (const u16*)x;
    int c = 0;
    for (int i = threadIdx.x; i < 4096; i += 256) {
        int e = (p[i] >> 7) & 0xFF;
        if (e >= 134) ++c;
    }
    atomicAdd(&cnt, c);
    __syncthreads();
    if (threadIdx.x == 0) flag[0] = (cnt > 100) ? 1 : 0;
}

// ---------------------------------------------------------------------------
// prep_w: Wt[j][tap][co][ci] bf16 from w_j OIHW (proven)
// ---------------------------------------------------------------------------
__global__ __launch_bounds__(256) void prep_w(
        const void* __restrict__ w0, const void* __restrict__ w1,
        const void* __restrict__ w2, u16* __restrict__ Wt,
        const int* __restrict__ flag) {
    int isf = flag[0];
    int i = blockIdx.x * 256 + threadIdx.x;
    if (i >= 442368) return;
    int j   = i / 147456;
    int rr  = i % 147456;
    int tap = rr >> 14;
    int co  = (rr >> 7) & 127;
    int ci  = rr & 127;
    const void* w = (j == 0) ? w0 : ((j == 1) ? w1 : w2);
    float v = loadf(w, (co * 128 + ci) * 9 + tap, isf);
    Wt[i] = f2bf(v);
}

// ---------------------------------------------------------------------------
// prep_ow: Wf f16 [co][ci] from 1x1 conv weight (16384 elems)
// ---------------------------------------------------------------------------
__global__ __launch_bounds__(256) void prep_ow(
        const void* __restrict__ ow, u16* __restrict__ Wf,
        const int* __restrict__ flag) {
    int isf = flag[0];
    int i = blockIdx.x * 256 + threadIdx.x;
    if (i < 16384) Wf[i] = f2h(loadf(ow, i, isf));
}

// ---------------------------------------------------------------------------
// prep_x: xT[b][pix][ci] bf16 from x[b][ci][pix] (proven)
// ---------------------------------------------------------------------------
__global__ __launch_bounds__(256) void prep_x(
        const void* __restrict__ x, u16* __restrict__ xT,
        const int* __restrict__ flag) {
    __shared__ float tile[32 * 129];
    int isf = flag[0];
    int t = threadIdx.x;
    int pixg = blockIdx.x, cig = blockIdx.y, b = blockIdx.z;

    int ci = t >> 3, px0 = (t & 7) * 16;
    int base = b * (NC * NPIX) + (cig * 32 + ci) * NPIX + pixg * 128 + px0;
#pragma unroll
    for (int u = 0; u < 4; ++u) {
        float4 v = load4(x, (base >> 2) + u, isf);
        float* d = &tile[ci * 129 + px0 + u * 4];
        d[0] = v.x; d[1] = v.y; d[2] = v.z; d[3] = v.w;
    }
    __syncthreads();
#pragma unroll
    for (int u = 0; u < 2; ++u) {
        int c = t + u * 256;
        int pix = c >> 2, seg = c & 3;
        u16 tmp[8];
#pragma unroll
        for (int e = 0; e < 8; ++e)
            tmp[e] = f2bf(tile[(seg * 8 + e) * 129 + pix]);
        size_t dst = ((size_t)(b * 1024 + pixg * 128 + pix)) * 128
                   + cig * 32 + seg * 8;
        *(ushort4*)&xT[dst]     = make_ushort4(tmp[0], tmp[1], tmp[2], tmp[3]);
        *(ushort4*)&xT[dst + 4] = make_ushort4(tmp[4], tmp[5], tmp[6], tmp[7]);
    }
}

// ---------------------------------------------------------------------------
// conv2: MFMA implicit-GEMM 3x3 conv (proven in round 4)
// ---------------------------------------------------------------------------
__global__ __launch_bounds__(256, 1) void conv2_kernel(
        const u16* __restrict__ xT, const u16* __restrict__ Wt,
        float* __restrict__ conv_out, float* __restrict__ stats) {
    __shared__ __align__(16) u16 Xh[322 * 128];
    __shared__ __align__(16) u16 WL[128 * 128];
    __shared__ float rs[8];

    int t = threadIdx.x;
    int pt = blockIdx.x, b = blockIdx.y, j = blockIdx.z;
    int p0 = pt * 256;
    int w = t >> 6, lane = t & 63;
    int q = lane >> 4, l16 = lane & 15;
    int cobase = (w & 1) * 64, pixbase = (w >> 1) * 128;

    const u16* xb = xT + (size_t)b * 1024 * 128;
#pragma unroll
    for (int k = 0; k < 21; ++k) {
        int c = t + k * 256;
        if (c < 322 * 16) {
            int row = c >> 4, seg = c & 15;
            int pg = p0 - 33 + row;
            uint4 v = make_uint4(0, 0, 0, 0);
            if (pg >= 0 && pg < 1024)
                v = *(const uint4*)(xb + (size_t)pg * 128 + seg * 8);
            *(uint4*)&Xh[row * 128 + ((seg + row) & 15) * 8] = v;
        }
    }
    const u16* wjb = Wt + (size_t)j * 9 * 16384;
#pragma unroll
    for (int k = 0; k < 8; ++k) {
        int c = t + k * 256;
        int co = c >> 4, seg = c & 15;
        uint4 v = *(const uint4*)(wjb + co * 128 + seg * 8);
        *(uint4*)&WL[co * 128 + ((seg + co) & 15) * 8] = v;
    }
    __syncthreads();

    f32x4 acc[4][8];
#pragma unroll
    for (int mt = 0; mt < 4; ++mt)
#pragma unroll
        for (int nt = 0; nt < 8; ++nt)
            acc[mt][nt] = (f32x4)0.f;

    uint4 wreg[8];
    for (int tap = 0; tap < 9; ++tap) {
        int dy = tap / 3, dx = tap % 3;
        if (tap < 8) {
            const u16* wn = wjb + (tap + 1) * 16384;
#pragma unroll
            for (int k = 0; k < 8; ++k) {
                int c = t + k * 256;
                wreg[k] = *(const uint4*)(wn + (c >> 4) * 128 + (c & 15) * 8);
            }
        }
        bool inv_e = (dx == 0) && (l16 == 0);
        bool inv_o = (dx == 2) && (l16 == 15);
        int rbase = pixbase + dy * 32 + dx + l16;

#pragma unroll
        for (int ks = 0; ks < 4; ++ks) {
            int sl = ks * 4 + q;
            short8 a[4], bf[8];
#pragma unroll
            for (int mt = 0; mt < 4; ++mt) {
                int row = cobase + mt * 16 + l16;
                a[mt] = *(const short8*)&WL[row * 128 + ((sl + row) & 15) * 8];
            }
#pragma unroll
            for (int nt = 0; nt < 8; ++nt) {
                int row = rbase + nt * 16;
                short8 v = *(const short8*)&Xh[row * 128 + ((sl + row) & 15) * 8];
                if ((nt & 1) ? inv_o : inv_e) v = (short8)0;
                bf[nt] = v;
            }
#pragma unroll
            for (int mt = 0; mt < 4; ++mt)
#pragma unroll
                for (int nt = 0; nt < 8; ++nt)
                    acc[mt][nt] = __builtin_amdgcn_mfma_f32_16x16x32_bf16(
                        a[mt], bf[nt], acc[mt][nt], 0, 0, 0);
        }
        __syncthreads();
        if (tap < 8) {
#pragma unroll
            for (int k = 0; k < 8; ++k) {
                int c = t + k * 256;
                *(uint4*)&WL[(c >> 4) * 128 + (((c & 15) + (c >> 4)) & 15) * 8]
                    = wreg[k];
            }
        }
        __syncthreads();
    }

    float s = 0.f, s2 = 0.f;
    size_t obase = ((size_t)(j * NB + b) * NC) * NPIX;
#pragma unroll
    for (int mt = 0; mt < 4; ++mt) {
#pragma unroll
        for (int nt = 0; nt < 8; ++nt) {
            f32x4 v = acc[mt][nt];
            int co  = cobase + mt * 16 + q * 4;
            int pix = p0 + pixbase + nt * 16 + l16;
#pragma unroll
            for (int r = 0; r < 4; ++r) {
                float val = v[r];
                conv_out[obase + (size_t)(co + r) * NPIX + pix] = val;
                s += val;
                s2 = fmaf(val, val, s2);
            }
        }
    }
#pragma unroll
    for (int off = 32; off; off >>= 1) {
        s  += __shfl_down(s,  (unsigned)off, 64);
        s2 += __shfl_down(s2, (unsigned)off, 64);
    }
    if (lane == 0) { rs[w] = s; rs[4 + w] = s2; }
    __syncthreads();
    if (t == 0) {
        atomicAdd(&stats[(j * NB + b) * 2 + 0], rs[0] + rs[1] + rs[2] + rs[3]);
        atomicAdd(&stats[(j * NB + b) * 2 + 1], rs[4] + rs[5] + rs[6] + rs[7]);
    }
}

// ---------------------------------------------------------------------------
// norm_kernel: GroupNorm(1) + exact GELU. Outputs f16 (proven round 7)
// ---------------------------------------------------------------------------
__global__ __launch_bounds__(256) void norm_kernel(
        const float* __restrict__ conv_out, const float* __restrict__ stats,
        const void* __restrict__ g0, const void* __restrict__ b0,
        const void* __restrict__ g1, const void* __restrict__ b1,
        const void* __restrict__ g2, const void* __restrict__ b2,
        u16* __restrict__ qh, u16* __restrict__ kh, u16* __restrict__ vh,
        const int* __restrict__ flag) {
    __shared__ float tile[32 * 257];
    int isf = flag[0];
    int t = threadIdx.x;
    int n0 = blockIdx.x * 256;
    int h = blockIdx.y;
    int z = blockIdx.z;
    int j = z >> 4;
    int b = z & 15;
    const void* gam = (j == 0) ? g0 : ((j == 1) ? g1 : g2);
    const void* bet = (j == 0) ? b0 : ((j == 1) ? b1 : b2);

    float sum = stats[z * 2], ss = stats[z * 2 + 1];
    const float inv = 1.0f / 131072.0f;
    float mean = sum * inv;
    float var  = fmaxf(ss * inv - mean * mean, 0.f);
    float rstd = rsqrtf(var + 1e-6f);

    const float* src = conv_out + ((size_t)z * NC + h * DH) * NPIX + n0;

    if (j == 2) {
        u16* dst = vh + (((size_t)(b * NH + h)) * DH) * NPIX + n0;
#pragma unroll
        for (int cl = 0; cl < 32; ++cl) {
            float v = src[cl * NPIX + t];
            v = (v - mean) * rstd * loadf(gam, h * DH + cl, isf)
              + loadf(bet, h * DH + cl, isf);
            v = 0.5f * v * (1.0f + erff(v * 0.70710678118654752f));
            dst[(size_t)cl * NPIX + t] = f2h(v);
        }
        return;
    }

#pragma unroll
    for (int cl = 0; cl < 32; ++cl) tile[cl * 257 + t] = src[cl * NPIX + t];
    __syncthreads();

    u16* dst = ((j == 0) ? qh : kh)
             + (((size_t)(b * NH + h)) * NPIX + n0) * DH;
#pragma unroll
    for (int k = 0; k < 32; ++k) {
        int o = t + k * 256;
        int d = o & 31, nl = o >> 5;
        float v = tile[d * 257 + nl];
        v = (v - mean) * rstd * loadf(gam, h * DH + d, isf)
          + loadf(bet, h * DH + d, isf);
        v = 0.5f * v * (1.0f + erff(v * 0.70710678118654752f));
        dst[o] = f2h(v);
    }
}

// ---------------------------------------------------------------------------
// bias_t kernel: biasT[h][m][n] = table[rel[n*1024+m]][h]  (bf16, proven)
// ---------------------------------------------------------------------------
__global__ __launch_bounds__(256) void biasT_kernel(
        const int* __restrict__ rel, const void* __restrict__ table,
        u16* __restrict__ biasT, const int* __restrict__ flag) {
    __shared__ int rl[64 * 65];
    int isf = flag[0];
    int t = threadIdx.x;
    int nt = blockIdx.x, mt = blockIdx.y;

#pragma unroll
    for (int c = 0; c < 16; ++c) {
        int i = t + c * 256;              // 4096
        int r = i >> 6, cc = i & 63;      // r=n-local, cc=m-local
        rl[r * 65 + cc] = rel[(size_t)(nt * 64 + r) * 1024 + mt * 64 + cc];
    }
    __syncthreads();

#pragma unroll
    for (int h = 0; h < NH; ++h) {
#pragma unroll
        for (int c = 0; c < 16; ++c) {
            int wdx = t + c * 256;        // 4096
            int m = wdx >> 6, n = wdx & 63;
            int ri = rl[n * 65 + m];
            float v = loadf(table, ri * NH + h, isf);
            biasT[((size_t)h << 20) + (size_t)(mt * 64 + m) * 1024
                  + nt * 64 + n] = f2bf(v);
        }
    }
}

// ---------------------------------------------------------------------------
// attn2: MFMA flash attention, zero LDS (proven round 7).
// Epilogue now writes attfh f16 [b][n][c] (B-operand layout for out3).
// ---------------------------------------------------------------------------
__global__ __launch_bounds__(256) void attn2_kernel(
        const u16* __restrict__ qh, const u16* __restrict__ kh,
        const u16* __restrict__ vh, const u16* __restrict__ biasT,
        u16* __restrict__ attfh) {
    int t = threadIdx.x;
    int b = blockIdx.x, h = blockIdx.y, qt = blockIdx.z;
    int w = t >> 6, lane = t & 63, q = lane >> 4, l16 = lane & 15;
    int nrow0 = qt * 128 + w * 32;

    const u16* qb = qh + (((size_t)(b * NH + h)) * NPIX) * DH;
    const u16* kb = kh + (((size_t)(b * NH + h)) * NPIX) * DH;
    const u16* vb = vh + (((size_t)(b * NH + h)) * DH) * NPIX;
    const u16* bb = biasT + ((size_t)h << 20);

    half8 qf[2];
#pragma unroll
    for (int nt = 0; nt < 2; ++nt)
        qf[nt] = *(const half8*)(qb + (size_t)(nrow0 + nt * 16 + l16) * DH
                                 + q * 8);

    f32x4 O[2][2];   // [dt][nt], O^T C-layout: col n=l16, row d=q*4+reg
#pragma unroll
    for (int dt = 0; dt < 2; ++dt)
#pragma unroll
        for (int nt = 0; nt < 2; ++nt) O[dt][nt] = (f32x4)0.f;
    float mrow[2] = {-1e30f, -1e30f}, lrow[2] = {0.f, 0.f};

    int addrLo = ((2 * (q & 1)) * 16 + l16) * 4;
    int addrHi = addrLo + 64;
    bool hiQ = (q >= 2);

    for (int kc = 0; kc < 8; ++kc) {
        int m0 = kc * 128;
        f32x4 St[8][2];
#pragma unroll
        for (int mt = 0; mt < 8; ++mt) {
            half8 kf = *(const half8*)(kb + (size_t)(m0 + mt * 16 + l16) * DH
                                       + q * 8);
            St[mt][0] = __builtin_amdgcn_mfma_f32_16x16x32_f16(
                kf, qf[0], (f32x4)0.f, 0, 0, 0);
            St[mt][1] = __builtin_amdgcn_mfma_f32_16x16x32_f16(
                kf, qf[1], (f32x4)0.f, 0, 0, 0);
        }
        float mx[2] = {-1e30f, -1e30f};
#pragma unroll
        for (int mt = 0; mt < 8; ++mt)
#pragma unroll
            for (int nt = 0; nt < 2; ++nt) {
                const u16* bp = bb + (size_t)(m0 + mt * 16 + q * 4) * 1024
                              + nrow0 + nt * 16 + l16;
#pragma unroll
                for (int r = 0; r < 4; ++r) {
                    float v = St[mt][nt][r] + bf2f(bp[(size_t)r * 1024]);
                    St[mt][nt][r] = v;
                    mx[nt] = fmaxf(mx[nt], v);
                }
            }
        float alpha[2];
#pragma unroll
        for (int nt = 0; nt < 2; ++nt) {
            mx[nt] = fmaxf(mx[nt], __shfl_xor(mx[nt], 16, 64));
            mx[nt] = fmaxf(mx[nt], __shfl_xor(mx[nt], 32, 64));
            float mn = fmaxf(mrow[nt], mx[nt]);
            alpha[nt] = __expf(mrow[nt] - mn);
            mrow[nt] = mn;
        }
        float sm[2] = {0.f, 0.f};
#pragma unroll
        for (int mt = 0; mt < 8; ++mt)
#pragma unroll
            for (int nt = 0; nt < 2; ++nt)
#pragma unroll
                for (int r = 0; r < 4; ++r) {
                    float p = __expf(St[mt][nt][r] - mrow[nt]);
                    St[mt][nt][r] = p;
                    sm[nt] += p;
                }
#pragma unroll
        for (int nt = 0; nt < 2; ++nt) {
            sm[nt] += __shfl_xor(sm[nt], 16, 64);
            sm[nt] += __shfl_xor(sm[nt], 32, 64);
            lrow[nt] = lrow[nt] * alpha[nt] + sm[nt];
        }
#pragma unroll
        for (int dt = 0; dt < 2; ++dt)
#pragma unroll
            for (int nt = 0; nt < 2; ++nt)
#pragma unroll
                for (int r = 0; r < 4; ++r)
                    O[dt][nt][r] *= alpha[nt];
#pragma unroll
        for (int ms = 0; ms < 4; ++ms) {
            half8 vf[2];
#pragma unroll
            for (int dt = 0; dt < 2; ++dt)
                vf[dt] = *(const half8*)(vb + (size_t)(dt * 16 + l16) * NPIX
                                         + m0 + ms * 32 + q * 8);
#pragma unroll
            for (int nt = 0; nt < 2; ++nt) {
                int p01_0 = pk_h2(St[2 * ms][nt][0],     St[2 * ms][nt][1]);
                int p23_0 = pk_h2(St[2 * ms][nt][2],     St[2 * ms][nt][3]);
                int p01_1 = pk_h2(St[2 * ms + 1][nt][0], St[2 * ms + 1][nt][1]);
                int p23_1 = pk_h2(St[2 * ms + 1][nt][2], St[2 * ms + 1][nt][3]);
                // FULL-EXEC bpermutes, then per-dest select (round-7 fix).
                int a0 = __builtin_amdgcn_ds_bpermute(addrLo, p01_0);
                int a1 = __builtin_amdgcn_ds_bpermute(addrLo, p23_0);
                int a2 = __builtin_amdgcn_ds_bpermute(addrHi, p01_0);
                int a3 = __builtin_amdgcn_ds_bpermute(addrHi, p23_0);
                int b0 = __builtin_amdgcn_ds_bpermute(addrLo, p01_1);
                int b1 = __builtin_amdgcn_ds_bpermute(addrLo, p23_1);
                int b2 = __builtin_amdgcn_ds_bpermute(addrHi, p01_1);
                int b3 = __builtin_amdgcn_ds_bpermute(addrHi, p23_1);
                int pb[4];
                pb[0] = hiQ ? b0 : a0;
                pb[1] = hiQ ? b1 : a1;
                pb[2] = hiQ ? b2 : a2;
                pb[3] = hiQ ? b3 : a3;
                half8 pf; __builtin_memcpy(&pf, pb, 16);
#pragma unroll
                for (int dt = 0; dt < 2; ++dt)
                    O[dt][nt] = __builtin_amdgcn_mfma_f32_16x16x32_f16(
                        vf[dt], pf, O[dt][nt], 0, 0, 0);
            }
        }
    }

    // ---- epilogue: attfh[b][n][c] f16 (8B packed stores) ----
#pragma unroll
    for (int nt = 0; nt < 2; ++nt) {
        float rl = 1.0f / lrow[nt];
        int n = nrow0 + nt * 16 + l16;
        u16* dst = attfh + ((size_t)b * NPIX + n) * NC + h * DH;
#pragma unroll
        for (int dt = 0; dt < 2; ++dt) {
            f32x4 o = O[dt][nt];
            uint2 pv = make_uint2((u32)pk_h2(o[0] * rl, o[1] * rl),
                                  (u32)pk_h2(o[2] * rl, o[3] * rl));
            *(uint2*)(dst + dt * 16 + q * 4) = pv;
        }
    }
}

// ---------------------------------------------------------------------------
// out3: MFMA 1x1 conv + bias, zero LDS. grid (16 ntiles, 16 b), 256 thr.
// Wf f16 [co][ci] (A), attfh f16 [b][n][ci] (B). Wave tile 64co x 32n.
// ---------------------------------------------------------------------------
__global__ __launch_bounds__(256) void out3_kernel(
        const u16* __restrict__ attfh, const u16* __restrict__ Wf,
        const void* __restrict__ ob, void* __restrict__ out,
        const int* __restrict__ flag) {
    int isf = flag[0];
    int t = threadIdx.x;
    int n0 = blockIdx.x * 64, b = blockIdx.y;
    int w = t >> 6, lane = t & 63, q = lane >> 4, l16 = lane & 15;
    int cobase = (w & 1) * 64, nbase = (w >> 1) * 32;

    f32x4 acc[4][2];
#pragma unroll
    for (int mt = 0; mt < 4; ++mt)
#pragma unroll
        for (int nt = 0; nt < 2; ++nt) acc[mt][nt] = (f32x4)0.f;

    const u16* ab = attfh + ((size_t)b * NPIX + n0 + nbase) * NC;
#pragma unroll
    for (int ks = 0; ks < 4; ++ks) {
        int k0 = ks * 32 + q * 8;
        half8 a[4], bfr[2];
#pragma unroll
        for (int mt = 0; mt < 4; ++mt)
            a[mt] = *(const half8*)(Wf + (size_t)(cobase + mt * 16 + l16) * NC
                                    + k0);
#pragma unroll
        for (int nt = 0; nt < 2; ++nt)
            bfr[nt] = *(const half8*)(ab + (size_t)(nt * 16 + l16) * NC + k0);
#pragma unroll
        for (int mt = 0; mt < 4; ++mt)
#pragma unroll
            for (int nt = 0; nt < 2; ++nt)
                acc[mt][nt] = __builtin_amdgcn_mfma_f32_16x16x32_f16(
                    a[mt], bfr[nt], acc[mt][nt], 0, 0, 0);
    }

    // epilogue: D[m=co][n], C-layout col n=l16, row co=q*4+reg
#pragma unroll
    for (int mt = 0; mt < 4; ++mt) {
#pragma unroll
        for (int nt = 0; nt < 2; ++nt) {
            f32x4 v = acc[mt][nt];
            int n = n0 + nbase + nt * 16 + l16;
#pragma unroll
            for (int r = 0; r < 4; ++r) {
                int co = cobase + mt * 16 + q * 4 + r;
                float val = v[r] + loadf(ob, co, isf);
                size_t oidx = ((size_t)b * NC + co) * NPIX + n;
                if (isf) ((float*)out)[oidx] = val;
                else     ((u16*)out)[oidx]   = f2bf(val);
            }
        }
    }
}

// ---------------------------------------------------------------------------
// Workspace (peak ~48 MiB, lifetime aliasing):
//   [0,448) stats | [448,452) flag
//   regQ = ws+512 (25,165,824 B):
//     xT bf16 8 MB @Q+0, Wt bf16 0.9 MB @Q+8388608   (prep -> conv2)
//     then qh f16 4 MB @Q+0, kh @Q+4M, vh @Q+8M      (norm -> attn2)
//     Wf f16 32 KB @Q+16777216                        (prep_ow -> out3)
//   regA = regQ+25165824 (25,165,824 B):
//     conv fp32 25 MB                                 (conv2 -> norm)
//     then biasT bf16 8 MB @A+0, attfh f16 4 MB @A+8388608
// Order: memset -> detect -> prep_w -> prep_ow -> prep_x -> conv2 -> norm ->
//        biasT -> attn2 -> out3
// ---------------------------------------------------------------------------
extern "C" void kernel_launch(void* const* d_in, const int* in_sizes, int n_in,
                              void* d_out, int out_size, void* d_ws,
                              size_t ws_size, hipStream_t stream) {
    (void)in_sizes; (void)n_in; (void)out_size; (void)ws_size;
    const void* x     = d_in[0];
    const void* wq    = d_in[1];
    const void* gq    = d_in[2];
    const void* bq    = d_in[3];
    const void* wk    = d_in[4];
    const void* gk    = d_in[5];
    const void* bk    = d_in[6];
    const void* wv    = d_in[7];
    const void* gv    = d_in[8];
    const void* bv    = d_in[9];
    const void* table = d_in[10];
    const int*  rel   = (const int*)d_in[11];
    const void* ow    = d_in[12];
    const void* ob    = d_in[13];

    char* ws = (char*)d_ws;
    float* stats = (float*)(ws);
    int*   flag  = (int*)(ws + 448);
    char*  regQ  = ws + 512;
    u16*   xT    = (u16*)regQ;
    u16*   Wt    = (u16*)(regQ + 8388608);
    u16*   qhp   = (u16*)regQ;                       // alias after conv2
    u16*   khp   = (u16*)(regQ + 4194304);
    u16*   vhp   = (u16*)(regQ + 8388608);
    u16*   Wf    = (u16*)(regQ + 16777216);          // prep_ow -> out3
    char*  regA  = regQ + 25165824;
    float* conv  = (float*)regA;                     // conv2 -> norm
    u16*   biasT = (u16*)regA;                       // alias after norm
    u16*   attfh = (u16*)(regA + 8388608);           // attn2 -> out3 (f16)

    (void)hipMemsetAsync(stats, 0, 96 * sizeof(float), stream);
    detect_kernel<<<1, 256, 0, stream>>>(x, flag);
    prep_w<<<1728, 256, 0, stream>>>(wq, wk, wv, Wt, flag);
    prep_ow<<<64, 256, 0, stream>>>(ow, Wf, flag);
    prep_x<<<dim3(8, 4, 16), 256, 0, stream>>>(x, xT, flag);
    conv2_kernel<<<dim3(4, 16, 3), 256, 0, stream>>>(xT, Wt, conv, stats);
    norm_kernel<<<dim3(4, 4, 48), 256, 0, stream>>>(conv, stats,
                                                    gq, bq, gk, bk, gv, bv,
                                                    qhp, khp, vhp, flag);
    biasT_kernel<<<dim3(16, 16), 256, 0, stream>>>(rel, table, biasT, flag);
    attn2_kernel<<<dim3(16, 4, 8), 256, 0, stream>>>(qhp, khp, vhp, biasT,
                                                     attfh);
    out3_kernel<<<dim3(16, 16), 256, 0, stream>>>(attfh, Wf, ob, d_out, flag);
}